// Round 1
// baseline (2053.009 us; speedup 1.0000x reference)
//
#include <hip/hip_runtime.h>
#include <math.h>

#define C_LEN 1024
#define NROW 4096   // B*C = 4*1024

__device__ __forceinline__ float siluf(float x) { return x / (1.f + expf(-x)); }

// ---------------- rmsnorm over rows of width 128 (one wave per row) ----------------
__global__ __launch_bounds__(256) void k_rmsnorm128(const float* __restrict__ x,
                                                    const float* __restrict__ w,
                                                    float* __restrict__ out) {
    int wave = threadIdx.x >> 6, lane = threadIdx.x & 63;
    int row = blockIdx.x * 4 + wave;
    float2 v = ((const float2*)(x + (size_t)row * 128))[lane];
    float ss = v.x * v.x + v.y * v.y;
    #pragma unroll
    for (int off = 32; off; off >>= 1) ss += __shfl_xor(ss, off, 64);
    float rs = rsqrtf(ss * (1.f / 128.f) + 1e-5f);
    float2 wv = ((const float2*)w)[lane];
    float2 o; o.x = v.x * rs * wv.x; o.y = v.y * rs * wv.y;
    ((float2*)(out + (size_t)row * 128))[lane] = o;
}

// ---------------- generic fp32 GEMM: C[M,N] = act(A[M,K] @ W[N,K]^T + bias) (+resid) -----
// flip!=0: logical row m reads physical A row with c -> C_LEN-1-c within its batch.
template<int ACT>
__global__ __launch_bounds__(256) void k_gemm(const float* __restrict__ A,
                                              const float* __restrict__ W,
                                              const float* __restrict__ bias,
                                              const float* __restrict__ resid,
                                              float* __restrict__ Cout,
                                              int M, int N, int K, int flip) {
    const int BM = 64, BN = 64, BK = 16;
    __shared__ float As[BK][BM + 4];
    __shared__ float Bs[BK][BN + 4];
    int tid = threadIdx.x;
    int m0 = blockIdx.y * BM, n0 = blockIdx.x * BN;
    int tx = tid & 15, ty = tid >> 4;
    int ldRow = tid >> 2;             // 0..63
    int ldC4  = (tid & 3) * 4;        // 0,4,8,12
    float acc[4][4] = {};

    for (int k0 = 0; k0 < K; k0 += BK) {
        int mLog = m0 + ldRow;
        int mPhys = flip ? ((mLog & ~(C_LEN - 1)) | ((C_LEN - 1) - (mLog & (C_LEN - 1)))) : mLog;
        float4 av = *(const float4*)(A + (size_t)mPhys * K + k0 + ldC4);
        As[ldC4 + 0][ldRow] = av.x; As[ldC4 + 1][ldRow] = av.y;
        As[ldC4 + 2][ldRow] = av.z; As[ldC4 + 3][ldRow] = av.w;

        int nIdx = n0 + ldRow;
        float4 wv = make_float4(0.f, 0.f, 0.f, 0.f);
        if (nIdx < N) wv = *(const float4*)(W + (size_t)nIdx * K + k0 + ldC4);
        Bs[ldC4 + 0][ldRow] = wv.x; Bs[ldC4 + 1][ldRow] = wv.y;
        Bs[ldC4 + 2][ldRow] = wv.z; Bs[ldC4 + 3][ldRow] = wv.w;
        __syncthreads();

        #pragma unroll
        for (int kk = 0; kk < BK; ++kk) {
            float ra[4], rb[4];
            #pragma unroll
            for (int i = 0; i < 4; ++i) ra[i] = As[kk][ty * 4 + i];
            #pragma unroll
            for (int j = 0; j < 4; ++j) rb[j] = Bs[kk][tx * 4 + j];
            #pragma unroll
            for (int i = 0; i < 4; ++i)
                #pragma unroll
                for (int j = 0; j < 4; ++j)
                    acc[i][j] = fmaf(ra[i], rb[j], acc[i][j]);
        }
        __syncthreads();
    }

    #pragma unroll
    for (int i = 0; i < 4; ++i) {
        int m = m0 + ty * 4 + i;
        #pragma unroll
        for (int j = 0; j < 4; ++j) {
            int nn = n0 + tx * 4 + j;
            if (nn < N) {
                float v = acc[i][j];
                if (bias) v += bias[nn];
                if (ACT == 1) v = v / (1.f + expf(-v));
                if (resid) v += resid[(size_t)m * N + nn];
                Cout[(size_t)m * N + nn] = v;
            }
        }
    }
}

// ---------------- causal depthwise conv (K=4) + silu: xz[:, :512] -> xconv ----------------
__global__ __launch_bounds__(256) void k_conv(const float* __restrict__ xz,
                                              const float* __restrict__ cw,
                                              const float* __restrict__ cb,
                                              float* __restrict__ xconv) {
    int d = blockIdx.x * 256 + threadIdx.x;   // 0..511
    int bc = blockIdx.y;                      // 0..4095
    int b = bc >> 10, c = bc & 1023;
    float acc = cb[d];
    #pragma unroll
    for (int k = 0; k < 4; ++k) {
        int cc = c - 3 + k;
        if (cc >= 0) acc = fmaf(cw[d * 4 + k], xz[((size_t)(b * C_LEN + cc)) * 1024 + d], acc);
    }
    xconv[(size_t)bc * 512 + d] = siluf(acc);
}

// ---------------- dt projection: dt = softplus(dbl[:, :16] @ dt_w^T + dt_b) ----------------
__global__ __launch_bounds__(256) void k_dtproj(const float* __restrict__ dbl,
                                                const float* __restrict__ dtw,
                                                const float* __restrict__ dtb,
                                                float* __restrict__ dt) {
    int d = blockIdx.x * 256 + threadIdx.x;   // 0..511
    int r = blockIdx.y;                       // 0..4095
    float s = dtb[d];
    const float* row = dbl + (size_t)r * 48;
    #pragma unroll
    for (int j = 0; j < 16; ++j) s = fmaf(row[j], dtw[d * 16 + j], s);
    float sp = fmaxf(s, 0.f) + log1pf(expf(-fabsf(s)));
    dt[(size_t)r * 512 + d] = sp;
}

// ---------------- selective scan + D skip + z gating ----------------
// block = 256 threads = 16 d-channels x 16 states. grid = 4 b * 32 dgroups = 128.
__global__ __launch_bounds__(256) void k_scan(const float* __restrict__ dt,
                                              const float* __restrict__ xconv,
                                              const float* __restrict__ dbl,
                                              const float* __restrict__ xz,
                                              const float* __restrict__ A_log,
                                              const float* __restrict__ Dp,
                                              float* __restrict__ gated) {
    int tid = threadIdx.x;
    int n = tid & 15, dl = tid >> 4;
    int b = blockIdx.x >> 5;
    int dg = blockIdx.x & 31;
    int d = dg * 16 + dl;
    float Acoef = -expf(A_log[d * 16 + n]);
    float Dd = Dp[d];
    float h = 0.f;
    for (int c = 0; c < C_LEN; ++c) {
        size_t r = (size_t)(b * C_LEN + c);
        float dtv = dt[r * 512 + d];
        float xv  = xconv[r * 512 + d];
        float Bv  = dbl[r * 48 + 16 + n];
        float Cv  = dbl[r * 48 + 32 + n];
        h = fmaf(expf(dtv * Acoef), h, dtv * xv * Bv);
        float contrib = h * Cv;
        #pragma unroll
        for (int off = 8; off; off >>= 1) contrib += __shfl_xor(contrib, off, 16);
        if (n == 0) {
            float y = contrib + xv * Dd;
            float zv = xz[r * 1024 + 512 + d];
            gated[r * 512 + d] = y * siluf(zv);
        }
    }
}

// ---------------- postnorm: rmsnorm(mo, w) + u, width 256 ----------------
__global__ __launch_bounds__(256) void k_postnorm(const float* __restrict__ mo,
                                                  const float* __restrict__ w,
                                                  const float* __restrict__ u,
                                                  float* __restrict__ out) {
    __shared__ float red[4];
    int r = blockIdx.x, tid = threadIdx.x;
    float v = mo[(size_t)r * 256 + tid];
    float ss = v * v;
    #pragma unroll
    for (int off = 32; off; off >>= 1) ss += __shfl_xor(ss, off, 64);
    if ((tid & 63) == 0) red[tid >> 6] = ss;
    __syncthreads();
    float tot = red[0] + red[1] + red[2] + red[3];
    float rs = rsqrtf(tot * (1.f / 256.f) + 1e-5f);
    out[(size_t)r * 256 + tid] = v * rs * w[tid] + u[(size_t)r * 256 + tid];
}

// ---------------- combine: comb = silu_w * (mo_f + flip_c(mo_b)) ----------------
__global__ __launch_bounds__(256) void k_comb(const float* __restrict__ wbuf,
                                              const float* __restrict__ mof,
                                              const float* __restrict__ mob,
                                              float* __restrict__ comb) {
    int r = blockIdx.x, tid = threadIdx.x;
    int b = r >> 10, c = r & 1023;
    int rb = (b << 10) | (1023 - c);
    comb[(size_t)r * 256 + tid] =
        wbuf[(size_t)r * 256 + tid] * (mof[(size_t)r * 256 + tid] + mob[(size_t)rb * 256 + tid]);
}

extern "C" void kernel_launch(void* const* d_in, const int* in_sizes, int n_in,
                              void* d_out, int out_size, void* d_ws, size_t ws_size,
                              hipStream_t stream) {
    const float* x          = (const float*)d_in[0];
    const float* W_in       = (const float*)d_in[1];
    const float* b_in       = (const float*)d_in[2];
    const float* W_wp       = (const float*)d_in[3];
    const float* b_wp       = (const float*)d_in[4];
    const float* W_fp       = (const float*)d_in[5];
    const float* b_fp       = (const float*)d_in[6];
    const float* W_bp       = (const float*)d_in[7];
    const float* b_bp       = (const float*)d_in[8];
    const float* W_out      = (const float*)d_in[9];
    const float* b_out      = (const float*)d_in[10];
    const float* norm_w_top = (const float*)d_in[11];
    // f params: 12..21, bk params: 22..31
    const float* mamba_p[2][10];
    for (int p = 0; p < 2; ++p)
        for (int i = 0; i < 10; ++i)
            mamba_p[p][i] = (const float*)d_in[12 + p * 10 + i];

    float* ws = (float*)d_ws;
    float* xn    = ws + 0;                       // 524288
    float* ssm   = ws + 524288;                  // 1048576
    float* uf    = ws + 1572864;                 // 1048576
    float* ub    = ws + 2621440;                 // 1048576
    float* mof   = ws + 3670016;                 // 1048576
    float* mob   = ws + 4718592;                 // 1048576
    float* xz    = ws + 5767168;                 // 4194304
    float* xconv = ws + 9961472;                 // 2097152
    float* dbl   = ws + 12058624;                // 196608
    float* dtb   = ws + 12255232;                // 2097152
    float* gated = ws + 14352384;                // 2097152 (end 16449536 floats = 62.7 MB)
    float* moraw = xz;                           // alias: xz dead after scan
    float* wbuf  = xz + 1048576;                 // alias
    float* comb  = xz + 2097152;                 // alias

    // 1. top rmsnorm
    k_rmsnorm128<<<NROW / 4, 256, 0, stream>>>(x, norm_w_top, xn);
    // 2. ssm_in = xn @ W_in^T + b_in        (M=4096,K=128,N=256)
    k_gemm<0><<<dim3(4, 64), 256, 0, stream>>>(xn, W_in, b_in, nullptr, ssm, NROW, 256, 128, 0);
    // 3. u_f = ssm @ W_fp^T + b_fp          (K=256,N=256)
    k_gemm<0><<<dim3(4, 64), 256, 0, stream>>>(ssm, W_fp, b_fp, nullptr, uf, NROW, 256, 256, 0);
    // 4. u_b = flip_c(ssm) @ W_bp^T + b_bp
    k_gemm<0><<<dim3(4, 64), 256, 0, stream>>>(ssm, W_bp, b_bp, nullptr, ub, NROW, 256, 256, 1);

    // 5/6. two mamba blocks (fwd on uf -> mof, bwd on ub -> mob)
    const float* u_of[2] = {uf, ub};
    float* mo_of[2] = {mof, mob};
    for (int p = 0; p < 2; ++p) {
        const float* in_w    = mamba_p[p][0];
        const float* conv_w  = mamba_p[p][1];
        const float* conv_b  = mamba_p[p][2];
        const float* xproj_w = mamba_p[p][3];
        const float* dt_w    = mamba_p[p][4];
        const float* dt_b    = mamba_p[p][5];
        const float* A_log   = mamba_p[p][6];
        const float* Dp      = mamba_p[p][7];
        const float* out_w   = mamba_p[p][8];
        const float* norm_w  = mamba_p[p][9];
        const float* u = u_of[p];

        // xz = u @ in_w^T                    (K=256,N=1024)
        k_gemm<0><<<dim3(16, 64), 256, 0, stream>>>(u, in_w, nullptr, nullptr, xz, NROW, 1024, 256, 0);
        // causal depthwise conv + silu
        k_conv<<<dim3(2, NROW), 256, 0, stream>>>(xz, conv_w, conv_b, xconv);
        // dbl = xconv @ xproj_w^T            (K=512,N=48)
        k_gemm<0><<<dim3(1, 64), 256, 0, stream>>>(xconv, xproj_w, nullptr, nullptr, dbl, NROW, 48, 512, 0);
        // dt = softplus(dbl[:, :16] @ dt_w^T + dt_b)
        k_dtproj<<<dim3(2, NROW), 256, 0, stream>>>(dbl, dt_w, dt_b, dtb);
        // selective scan + D skip + z gate
        k_scan<<<128, 256, 0, stream>>>(dtb, xconv, dbl, xz, A_log, Dp, gated);
        // mo_raw = gated @ out_w^T           (K=512,N=256)
        k_gemm<0><<<dim3(4, 64), 256, 0, stream>>>(gated, out_w, nullptr, nullptr, moraw, NROW, 256, 512, 0);
        // postnorm: rmsnorm(mo_raw)*norm_w + u
        k_postnorm<<<NROW, 256, 0, stream>>>(moraw, norm_w, u, mo_of[p]);
    }

    // 7. wbuf = silu(xn @ W_wp^T + b_wp)     (K=128,N=256)
    k_gemm<1><<<dim3(4, 64), 256, 0, stream>>>(xn, W_wp, b_wp, nullptr, wbuf, NROW, 256, 128, 0);
    // 8. comb = wbuf * (mof + flip_c(mob))
    k_comb<<<NROW, 256, 0, stream>>>(wbuf, mof, mob, comb);
    // 9. out = comb @ W_out^T + b_out + x    (K=256,N=128)
    k_gemm<0><<<dim3(2, 64), 256, 0, stream>>>(comb, W_out, b_out, x, (float*)d_out, NROW, 128, 256, 0);
}

// Round 2
// 620.940 us; speedup vs baseline: 3.3063x; 3.3063x over previous
//
#include <hip/hip_runtime.h>
#include <math.h>

#define C_LEN 1024
#define NROW 4096   // B*C = 4*1024
#define NCHUNK 16
#define CHUNK 64    // C_LEN / NCHUNK

__device__ __forceinline__ float siluf(float x) { return x / (1.f + expf(-x)); }

// ---------------- rmsnorm over rows of width 128 (one wave per row) ----------------
__global__ __launch_bounds__(256) void k_rmsnorm128(const float* __restrict__ x,
                                                    const float* __restrict__ w,
                                                    float* __restrict__ out) {
    int wave = threadIdx.x >> 6, lane = threadIdx.x & 63;
    int row = blockIdx.x * 4 + wave;
    float2 v = ((const float2*)(x + (size_t)row * 128))[lane];
    float ss = v.x * v.x + v.y * v.y;
    #pragma unroll
    for (int off = 32; off; off >>= 1) ss += __shfl_xor(ss, off, 64);
    float rs = rsqrtf(ss * (1.f / 128.f) + 1e-5f);
    float2 wv = ((const float2*)w)[lane];
    float2 o; o.x = v.x * rs * wv.x; o.y = v.y * rs * wv.y;
    ((float2*)(out + (size_t)row * 128))[lane] = o;
}

// ---------------- generic fp32 GEMM: C[M,N] = act(A[M,K] @ W[N,K]^T + bias) (+resid) -----
// flip!=0: logical row m reads physical A row with c -> C_LEN-1-c within its batch.
template<int ACT>
__global__ __launch_bounds__(256) void k_gemm(const float* __restrict__ A,
                                              const float* __restrict__ W,
                                              const float* __restrict__ bias,
                                              const float* __restrict__ resid,
                                              float* __restrict__ Cout,
                                              int M, int N, int K, int flip) {
    const int BM = 64, BN = 64, BK = 16;
    __shared__ float As[BK][BM + 4];
    __shared__ float Bs[BK][BN + 4];
    int tid = threadIdx.x;
    int m0 = blockIdx.y * BM, n0 = blockIdx.x * BN;
    int tx = tid & 15, ty = tid >> 4;
    int ldRow = tid >> 2;             // 0..63
    int ldC4  = (tid & 3) * 4;        // 0,4,8,12
    float acc[4][4] = {};

    for (int k0 = 0; k0 < K; k0 += BK) {
        int mLog = m0 + ldRow;
        int mPhys = flip ? ((mLog & ~(C_LEN - 1)) | ((C_LEN - 1) - (mLog & (C_LEN - 1)))) : mLog;
        float4 av = *(const float4*)(A + (size_t)mPhys * K + k0 + ldC4);
        As[ldC4 + 0][ldRow] = av.x; As[ldC4 + 1][ldRow] = av.y;
        As[ldC4 + 2][ldRow] = av.z; As[ldC4 + 3][ldRow] = av.w;

        int nIdx = n0 + ldRow;
        float4 wv = make_float4(0.f, 0.f, 0.f, 0.f);
        if (nIdx < N) wv = *(const float4*)(W + (size_t)nIdx * K + k0 + ldC4);
        Bs[ldC4 + 0][ldRow] = wv.x; Bs[ldC4 + 1][ldRow] = wv.y;
        Bs[ldC4 + 2][ldRow] = wv.z; Bs[ldC4 + 3][ldRow] = wv.w;
        __syncthreads();

        #pragma unroll
        for (int kk = 0; kk < BK; ++kk) {
            float ra[4], rb[4];
            #pragma unroll
            for (int i = 0; i < 4; ++i) ra[i] = As[kk][ty * 4 + i];
            #pragma unroll
            for (int j = 0; j < 4; ++j) rb[j] = Bs[kk][tx * 4 + j];
            #pragma unroll
            for (int i = 0; i < 4; ++i)
                #pragma unroll
                for (int j = 0; j < 4; ++j)
                    acc[i][j] = fmaf(ra[i], rb[j], acc[i][j]);
        }
        __syncthreads();
    }

    #pragma unroll
    for (int i = 0; i < 4; ++i) {
        int m = m0 + ty * 4 + i;
        #pragma unroll
        for (int j = 0; j < 4; ++j) {
            int nn = n0 + tx * 4 + j;
            if (nn < N) {
                float v = acc[i][j];
                if (bias) v += bias[nn];
                if (ACT == 1) v = v / (1.f + expf(-v));
                if (resid) v += resid[(size_t)m * N + nn];
                Cout[(size_t)m * N + nn] = v;
            }
        }
    }
}

// ---------------- causal depthwise conv (K=4) + silu: xz[:, :512] -> xconv ----------------
__global__ __launch_bounds__(256) void k_conv(const float* __restrict__ xz,
                                              const float* __restrict__ cw,
                                              const float* __restrict__ cb,
                                              float* __restrict__ xconv) {
    int d = blockIdx.x * 256 + threadIdx.x;   // 0..511
    int bc = blockIdx.y;                      // 0..4095
    int b = bc >> 10, c = bc & 1023;
    float acc = cb[d];
    #pragma unroll
    for (int k = 0; k < 4; ++k) {
        int cc = c - 3 + k;
        if (cc >= 0) acc = fmaf(cw[d * 4 + k], xz[((size_t)(b * C_LEN + cc)) * 1024 + d], acc);
    }
    xconv[(size_t)bc * 512 + d] = siluf(acc);
}

// ---------------- dt projection: dt = softplus(dbl[:, :16] @ dt_w^T + dt_b) ----------------
__global__ __launch_bounds__(256) void k_dtproj(const float* __restrict__ dbl,
                                                const float* __restrict__ dtw,
                                                const float* __restrict__ dtb,
                                                float* __restrict__ dt) {
    int d = blockIdx.x * 256 + threadIdx.x;   // 0..511
    int r = blockIdx.y;                       // 0..4095
    float s = dtb[d];
    const float* row = dbl + (size_t)r * 48;
    #pragma unroll
    for (int j = 0; j < 16; ++j) s = fmaf(row[j], dtw[d * 16 + j], s);
    float sp = fmaxf(s, 0.f) + log1pf(expf(-fabsf(s)));
    dt[(size_t)r * 512 + d] = sp;
}

// ---------------- chunked selective scan, pass 1: local scan per chunk ----------------
// block = 256 = 16 d x 16 n. grid = (16 chunks, 32 dgroups, 4 b).
// emits hfin[b][k][d][n], Pfin[b][k][d][n] (decay product over the chunk).
__global__ __launch_bounds__(256) void k_scan1(const float* __restrict__ dt,
                                               const float* __restrict__ xconv,
                                               const float* __restrict__ dbl,
                                               const float* __restrict__ A_log,
                                               float* __restrict__ hfin,
                                               float* __restrict__ Pfin) {
    int tid = threadIdx.x;
    int n = tid & 15, dl = tid >> 4;
    int k = blockIdx.x, dg = blockIdx.y, b = blockIdx.z;
    int d = dg * 16 + dl;
    float Acoef = -expf(A_log[d * 16 + n]);
    float h = 0.f, P = 1.f;
    int c0 = k * CHUNK;
    #pragma unroll 4
    for (int c = c0; c < c0 + CHUNK; ++c) {
        size_t r = (size_t)(b * C_LEN + c);
        float dtv = dt[r * 512 + d];
        float xv  = xconv[r * 512 + d];
        float Bv  = dbl[r * 48 + 16 + n];
        float a = expf(dtv * Acoef);
        h = fmaf(a, h, dtv * xv * Bv);
        P *= a;
    }
    size_t idx = ((size_t)(b * NCHUNK + k) * 512 + d) * 16 + n;
    hfin[idx] = h;
    Pfin[idx] = P;
}

// ---------------- pass 2: sequential combine over chunks; writes carry-in into Pfin --------
// one thread per (b,d,n) = 32768 threads.
__global__ __launch_bounds__(256) void k_scan2(const float* __restrict__ hfin,
                                               float* __restrict__ Pfin) {
    int t = blockIdx.x * 256 + threadIdx.x;   // (b*512+d)*16+n
    int b = t >> 13;
    int dn = t & 8191;
    float carry = 0.f;
    #pragma unroll
    for (int k = 0; k < NCHUNK; ++k) {
        size_t idx = (size_t)(b * NCHUNK + k) * 8192 + dn;
        float p = Pfin[idx];
        float hf = hfin[idx];
        Pfin[idx] = carry;                    // carry-in for chunk k
        carry = fmaf(p, carry, hf);
    }
}

// ---------------- pass 3: replay chunk with carry-in; emit y + D skip + z gate ------------
__global__ __launch_bounds__(256) void k_scan3(const float* __restrict__ dt,
                                               const float* __restrict__ xconv,
                                               const float* __restrict__ dbl,
                                               const float* __restrict__ xz,
                                               const float* __restrict__ A_log,
                                               const float* __restrict__ Dp,
                                               const float* __restrict__ carryArr,
                                               float* __restrict__ gated) {
    int tid = threadIdx.x;
    int n = tid & 15, dl = tid >> 4;
    int k = blockIdx.x, dg = blockIdx.y, b = blockIdx.z;
    int d = dg * 16 + dl;
    float Acoef = -expf(A_log[d * 16 + n]);
    float Dd = Dp[d];
    float h = carryArr[((size_t)(b * NCHUNK + k) * 512 + d) * 16 + n];
    int c0 = k * CHUNK;
    for (int c = c0; c < c0 + CHUNK; ++c) {
        size_t r = (size_t)(b * C_LEN + c);
        float dtv = dt[r * 512 + d];
        float xv  = xconv[r * 512 + d];
        float Bv  = dbl[r * 48 + 16 + n];
        float Cv  = dbl[r * 48 + 32 + n];
        h = fmaf(expf(dtv * Acoef), h, dtv * xv * Bv);
        float contrib = h * Cv;
        #pragma unroll
        for (int off = 8; off; off >>= 1) contrib += __shfl_xor(contrib, off, 16);
        if (n == 0) {
            float y = contrib + xv * Dd;
            float zv = xz[r * 1024 + 512 + d];
            gated[r * 512 + d] = y * siluf(zv);
        }
    }
}

// ---------------- postnorm: rmsnorm(mo, w) + u, width 256 ----------------
__global__ __launch_bounds__(256) void k_postnorm(const float* __restrict__ mo,
                                                  const float* __restrict__ w,
                                                  const float* __restrict__ u,
                                                  float* __restrict__ out) {
    __shared__ float red[4];
    int r = blockIdx.x, tid = threadIdx.x;
    float v = mo[(size_t)r * 256 + tid];
    float ss = v * v;
    #pragma unroll
    for (int off = 32; off; off >>= 1) ss += __shfl_xor(ss, off, 64);
    if ((tid & 63) == 0) red[tid >> 6] = ss;
    __syncthreads();
    float tot = red[0] + red[1] + red[2] + red[3];
    float rs = rsqrtf(tot * (1.f / 256.f) + 1e-5f);
    out[(size_t)r * 256 + tid] = v * rs * w[tid] + u[(size_t)r * 256 + tid];
}

// ---------------- combine: comb = silu_w * (mo_f + flip_c(mo_b)) ----------------
__global__ __launch_bounds__(256) void k_comb(const float* __restrict__ wbuf,
                                              const float* __restrict__ mof,
                                              const float* __restrict__ mob,
                                              float* __restrict__ comb) {
    int r = blockIdx.x, tid = threadIdx.x;
    int b = r >> 10, c = r & 1023;
    int rb = (b << 10) | (1023 - c);
    comb[(size_t)r * 256 + tid] =
        wbuf[(size_t)r * 256 + tid] * (mof[(size_t)r * 256 + tid] + mob[(size_t)rb * 256 + tid]);
}

extern "C" void kernel_launch(void* const* d_in, const int* in_sizes, int n_in,
                              void* d_out, int out_size, void* d_ws, size_t ws_size,
                              hipStream_t stream) {
    const float* x          = (const float*)d_in[0];
    const float* W_in       = (const float*)d_in[1];
    const float* b_in       = (const float*)d_in[2];
    const float* W_wp       = (const float*)d_in[3];
    const float* b_wp       = (const float*)d_in[4];
    const float* W_fp       = (const float*)d_in[5];
    const float* b_fp       = (const float*)d_in[6];
    const float* W_bp       = (const float*)d_in[7];
    const float* b_bp       = (const float*)d_in[8];
    const float* W_out      = (const float*)d_in[9];
    const float* b_out      = (const float*)d_in[10];
    const float* norm_w_top = (const float*)d_in[11];
    const float* mamba_p[2][10];
    for (int p = 0; p < 2; ++p)
        for (int i = 0; i < 10; ++i)
            mamba_p[p][i] = (const float*)d_in[12 + p * 10 + i];

    float* ws = (float*)d_ws;
    float* xn    = ws + 0;                       // 524288
    float* ssm   = ws + 524288;                  // 1048576 (dead after step 4 -> reused below)
    float* uf    = ws + 1572864;                 // 1048576
    float* ub    = ws + 2621440;                 // 1048576
    float* mof   = ws + 3670016;                 // 1048576
    float* mob   = ws + 4718592;                 // 1048576
    float* xz    = ws + 5767168;                 // 4194304
    float* xconv = ws + 9961472;                 // 2097152
    float* dbl   = ws + 12058624;                // 196608
    float* dtb   = ws + 12255232;                // 2097152
    float* gated = ws + 14352384;                // 2097152 (end 16449536 floats = 62.7 MB)
    float* moraw = xz;                           // alias: xz dead after scan
    float* wbuf  = xz + 1048576;                 // alias
    float* comb  = xz + 2097152;                 // alias
    float* hfin  = ssm;                          // alias: ssm dead after uf/ub GEMMs (524288)
    float* Pfin  = ssm + 524288;                 // (524288)

    // 1. top rmsnorm
    k_rmsnorm128<<<NROW / 4, 256, 0, stream>>>(x, norm_w_top, xn);
    // 2. ssm_in = xn @ W_in^T + b_in        (M=4096,K=128,N=256)
    k_gemm<0><<<dim3(4, 64), 256, 0, stream>>>(xn, W_in, b_in, nullptr, ssm, NROW, 256, 128, 0);
    // 3. u_f = ssm @ W_fp^T + b_fp          (K=256,N=256)
    k_gemm<0><<<dim3(4, 64), 256, 0, stream>>>(ssm, W_fp, b_fp, nullptr, uf, NROW, 256, 256, 0);
    // 4. u_b = flip_c(ssm) @ W_bp^T + b_bp
    k_gemm<0><<<dim3(4, 64), 256, 0, stream>>>(ssm, W_bp, b_bp, nullptr, ub, NROW, 256, 256, 1);

    // 5/6. two mamba blocks (fwd on uf -> mof, bwd on ub -> mob)
    const float* u_of[2] = {uf, ub};
    float* mo_of[2] = {mof, mob};
    for (int p = 0; p < 2; ++p) {
        const float* in_w    = mamba_p[p][0];
        const float* conv_w  = mamba_p[p][1];
        const float* conv_b  = mamba_p[p][2];
        const float* xproj_w = mamba_p[p][3];
        const float* dt_w    = mamba_p[p][4];
        const float* dt_b    = mamba_p[p][5];
        const float* A_log   = mamba_p[p][6];
        const float* Dp      = mamba_p[p][7];
        const float* out_w   = mamba_p[p][8];
        const float* norm_w  = mamba_p[p][9];
        const float* u = u_of[p];

        // xz = u @ in_w^T                    (K=256,N=1024)
        k_gemm<0><<<dim3(16, 64), 256, 0, stream>>>(u, in_w, nullptr, nullptr, xz, NROW, 1024, 256, 0);
        // causal depthwise conv + silu
        k_conv<<<dim3(2, NROW), 256, 0, stream>>>(xz, conv_w, conv_b, xconv);
        // dbl = xconv @ xproj_w^T            (K=512,N=48)
        k_gemm<0><<<dim3(1, 64), 256, 0, stream>>>(xconv, xproj_w, nullptr, nullptr, dbl, NROW, 48, 512, 0);
        // dt = softplus(dbl[:, :16] @ dt_w^T + dt_b)
        k_dtproj<<<dim3(2, NROW), 256, 0, stream>>>(dbl, dt_w, dt_b, dtb);
        // chunked selective scan (3 passes)
        k_scan1<<<dim3(NCHUNK, 32, 4), 256, 0, stream>>>(dtb, xconv, dbl, A_log, hfin, Pfin);
        k_scan2<<<128, 256, 0, stream>>>(hfin, Pfin);
        k_scan3<<<dim3(NCHUNK, 32, 4), 256, 0, stream>>>(dtb, xconv, dbl, xz, A_log, Dp, Pfin, gated);
        // mo_raw = gated @ out_w^T           (K=512,N=256)
        k_gemm<0><<<dim3(4, 64), 256, 0, stream>>>(gated, out_w, nullptr, nullptr, moraw, NROW, 256, 512, 0);
        // postnorm: rmsnorm(mo_raw)*norm_w + u
        k_postnorm<<<NROW, 256, 0, stream>>>(moraw, norm_w, u, mo_of[p]);
    }

    // 7. wbuf = silu(xn @ W_wp^T + b_wp)     (K=128,N=256)
    k_gemm<1><<<dim3(4, 64), 256, 0, stream>>>(xn, W_wp, b_wp, nullptr, wbuf, NROW, 256, 128, 0);
    // 8. comb = wbuf * (mof + flip_c(mob))
    k_comb<<<NROW, 256, 0, stream>>>(wbuf, mof, mob, comb);
    // 9. out = comb @ W_out^T + b_out + x    (K=256,N=128)
    k_gemm<0><<<dim3(2, 64), 256, 0, stream>>>(comb, W_out, b_out, x, (float*)d_out, NROW, 128, 256, 0);
}

// Round 3
// 594.804 us; speedup vs baseline: 3.4516x; 1.0439x over previous
//
#include <hip/hip_runtime.h>
#include <math.h>

#define C_LEN 1024
#define NROW 4096   // B*C = 4*1024
#define NCHUNK 16
#define CHUNK 64    // C_LEN / NCHUNK

__device__ __forceinline__ float siluf(float x) { return x / (1.f + __expf(-x)); }

// ---------------- rmsnorm over rows of width 128 (one wave per row) ----------------
__global__ __launch_bounds__(256) void k_rmsnorm128(const float* __restrict__ x,
                                                    const float* __restrict__ w,
                                                    float* __restrict__ out) {
    int wave = threadIdx.x >> 6, lane = threadIdx.x & 63;
    int row = blockIdx.x * 4 + wave;
    float2 v = ((const float2*)(x + (size_t)row * 128))[lane];
    float ss = v.x * v.x + v.y * v.y;
    #pragma unroll
    for (int off = 32; off; off >>= 1) ss += __shfl_xor(ss, off, 64);
    float rs = rsqrtf(ss * (1.f / 128.f) + 1e-5f);
    float2 wv = ((const float2*)w)[lane];
    float2 o; o.x = v.x * rs * wv.x; o.y = v.y * rs * wv.y;
    ((float2*)(out + (size_t)row * 128))[lane] = o;
}

// ---------------- generic fp32 GEMM: C[M,N] = act(A[M,K] @ W[N,K]^T + bias) (+resid) -----
// flip!=0: logical row m reads physical A row with c -> C_LEN-1-c within its batch.
template<int ACT>
__global__ __launch_bounds__(256) void k_gemm(const float* __restrict__ A,
                                              const float* __restrict__ W,
                                              const float* __restrict__ bias,
                                              const float* __restrict__ resid,
                                              float* __restrict__ Cout,
                                              int M, int N, int K, int flip) {
    const int BM = 64, BN = 64, BK = 16;
    __shared__ float As[BK][BM + 4];
    __shared__ float Bs[BK][BN + 4];
    int tid = threadIdx.x;
    int m0 = blockIdx.y * BM, n0 = blockIdx.x * BN;
    int tx = tid & 15, ty = tid >> 4;
    int ldRow = tid >> 2;             // 0..63
    int ldC4  = (tid & 3) * 4;        // 0,4,8,12
    float acc[4][4] = {};

    for (int k0 = 0; k0 < K; k0 += BK) {
        int mLog = m0 + ldRow;
        int mPhys = flip ? ((mLog & ~(C_LEN - 1)) | ((C_LEN - 1) - (mLog & (C_LEN - 1)))) : mLog;
        float4 av = *(const float4*)(A + (size_t)mPhys * K + k0 + ldC4);
        As[ldC4 + 0][ldRow] = av.x; As[ldC4 + 1][ldRow] = av.y;
        As[ldC4 + 2][ldRow] = av.z; As[ldC4 + 3][ldRow] = av.w;

        int nIdx = n0 + ldRow;
        float4 wv = make_float4(0.f, 0.f, 0.f, 0.f);
        if (nIdx < N) wv = *(const float4*)(W + (size_t)nIdx * K + k0 + ldC4);
        Bs[ldC4 + 0][ldRow] = wv.x; Bs[ldC4 + 1][ldRow] = wv.y;
        Bs[ldC4 + 2][ldRow] = wv.z; Bs[ldC4 + 3][ldRow] = wv.w;
        __syncthreads();

        #pragma unroll
        for (int kk = 0; kk < BK; ++kk) {
            float ra[4], rb[4];
            #pragma unroll
            for (int i = 0; i < 4; ++i) ra[i] = As[kk][ty * 4 + i];
            #pragma unroll
            for (int j = 0; j < 4; ++j) rb[j] = Bs[kk][tx * 4 + j];
            #pragma unroll
            for (int i = 0; i < 4; ++i)
                #pragma unroll
                for (int j = 0; j < 4; ++j)
                    acc[i][j] = fmaf(ra[i], rb[j], acc[i][j]);
        }
        __syncthreads();
    }

    #pragma unroll
    for (int i = 0; i < 4; ++i) {
        int m = m0 + ty * 4 + i;
        #pragma unroll
        for (int j = 0; j < 4; ++j) {
            int nn = n0 + tx * 4 + j;
            if (nn < N) {
                float v = acc[i][j];
                if (bias) v += bias[nn];
                if (ACT == 1) v = siluf(v);
                if (resid) v += resid[(size_t)m * N + nn];
                Cout[(size_t)m * N + nn] = v;
            }
        }
    }
}

// ---------------- causal depthwise conv (K=4) + silu: xz[:, :512] -> xconv ----------------
__global__ __launch_bounds__(256) void k_conv(const float* __restrict__ xz,
                                              const float* __restrict__ cw,
                                              const float* __restrict__ cb,
                                              float* __restrict__ xconv) {
    int d = blockIdx.x * 256 + threadIdx.x;   // 0..511
    int bc = blockIdx.y;                      // 0..4095
    int b = bc >> 10, c = bc & 1023;
    float acc = cb[d];
    const float* base = xz + (size_t)(b * C_LEN) * 1024 + d;
    #pragma unroll
    for (int k = 0; k < 4; ++k) {
        int cc = c - 3 + k;
        if (cc >= 0) acc = fmaf(cw[d * 4 + k], base[(size_t)cc * 1024], acc);
    }
    xconv[(size_t)bc * 512 + d] = siluf(acc);
}

// ---------------- dt projection: dt = softplus(dbl[:, :16] @ dt_w^T + dt_b) ----------------
__global__ __launch_bounds__(256) void k_dtproj(const float* __restrict__ dbl,
                                                const float* __restrict__ dtw,
                                                const float* __restrict__ dtb,
                                                float* __restrict__ dt) {
    int d = blockIdx.x * 256 + threadIdx.x;   // 0..511
    int r = blockIdx.y;                       // 0..4095
    float s = dtb[d];
    const float* row = dbl + (size_t)r * 48;
    #pragma unroll
    for (int j = 0; j < 16; ++j) s = fmaf(row[j], dtw[d * 16 + j], s);
    float sp = fmaxf(s, 0.f) + log1pf(__expf(-fabsf(s)));
    dt[(size_t)r * 512 + d] = sp;
}

// ---------------- chunked selective scan, pass 1: local scan per chunk ----------------
// block = 256 = 16 d x 16 n. grid = (16 chunks, 32 dgroups, 4 b).
// emits hfin[b][k][d][n], Pfin[b][k][d][n] (decay product over the chunk).
__global__ __launch_bounds__(256) void k_scan1(const float* __restrict__ dt,
                                               const float* __restrict__ xconv,
                                               const float* __restrict__ dbl,
                                               const float* __restrict__ A_log,
                                               float* __restrict__ hfin,
                                               float* __restrict__ Pfin) {
    int tid = threadIdx.x;
    int n = tid & 15, dl = tid >> 4;
    int k = blockIdx.x, dg = blockIdx.y, b = blockIdx.z;
    int d = dg * 16 + dl;
    float Acoef = -__expf(A_log[d * 16 + n]);
    int c0 = k * CHUNK;
    size_t r0 = (size_t)(b * C_LEN + c0);
    const float* pdt = dt + r0 * 512 + d;
    const float* pxv = xconv + r0 * 512 + d;
    const float* pB  = dbl + r0 * 48 + 16 + n;
    float h = 0.f, sdt = 0.f;
    #pragma unroll 8
    for (int c = 0; c < CHUNK; ++c) {
        float dtv = *pdt;
        float xv  = *pxv;
        float Bv  = *pB;
        float a = __expf(dtv * Acoef);
        h = fmaf(a, h, dtv * xv * Bv);
        sdt += dtv;
        pdt += 512; pxv += 512; pB += 48;
    }
    size_t idx = ((size_t)(b * NCHUNK + k) * 512 + d) * 16 + n;
    hfin[idx] = h;
    Pfin[idx] = __expf(Acoef * sdt);
}

// ---------------- pass 2: sequential combine over chunks; writes carry-in into Pfin --------
// one thread per (b,d,n) = 32768 threads.
__global__ __launch_bounds__(256) void k_scan2(const float* __restrict__ hfin,
                                               float* __restrict__ Pfin) {
    int t = blockIdx.x * 256 + threadIdx.x;   // (b*512+d)*16+n
    int b = t >> 13;
    int dn = t & 8191;
    float carry = 0.f;
    #pragma unroll
    for (int k = 0; k < NCHUNK; ++k) {
        size_t idx = (size_t)(b * NCHUNK + k) * 8192 + dn;
        float p = Pfin[idx];
        float hf = hfin[idx];
        Pfin[idx] = carry;                    // carry-in for chunk k
        carry = fmaf(p, carry, hf);
    }
}

// ---------------- pass 3: replay chunk with carry-in; emit y + D skip + z gate ------------
__global__ __launch_bounds__(256) void k_scan3(const float* __restrict__ dt,
                                               const float* __restrict__ xconv,
                                               const float* __restrict__ dbl,
                                               const float* __restrict__ xz,
                                               const float* __restrict__ A_log,
                                               const float* __restrict__ Dp,
                                               const float* __restrict__ carryArr,
                                               float* __restrict__ gated) {
    int tid = threadIdx.x;
    int n = tid & 15, dl = tid >> 4;
    int k = blockIdx.x, dg = blockIdx.y, b = blockIdx.z;
    int d = dg * 16 + dl;
    float Acoef = -__expf(A_log[d * 16 + n]);
    float Dd = Dp[d];
    float h = carryArr[((size_t)(b * NCHUNK + k) * 512 + d) * 16 + n];
    int c0 = k * CHUNK;
    size_t r0 = (size_t)(b * C_LEN + c0);
    const float* pdt = dt + r0 * 512 + d;
    const float* pxv = xconv + r0 * 512 + d;
    const float* pB  = dbl + r0 * 48 + 16 + n;
    const float* pC  = dbl + r0 * 48 + 32 + n;
    const float* pz  = xz + r0 * 1024 + 512 + d;
    float* pg        = gated + r0 * 512 + d;
    #pragma unroll 4
    for (int c = 0; c < CHUNK; ++c) {
        float dtv = *pdt;
        float xv  = *pxv;
        float Bv  = *pB;
        float Cv  = *pC;
        h = fmaf(__expf(dtv * Acoef), h, dtv * xv * Bv);
        float contrib = h * Cv;
        #pragma unroll
        for (int off = 8; off; off >>= 1) contrib += __shfl_xor(contrib, off, 16);
        if (n == 0) {
            float y = contrib + xv * Dd;
            float zv = *pz;
            *pg = y * siluf(zv);
        }
        pdt += 512; pxv += 512; pB += 48; pC += 48; pz += 1024; pg += 512;
    }
}

// ---------------- postnorm: rmsnorm(mo, w) + u, width 256 ----------------
__global__ __launch_bounds__(256) void k_postnorm(const float* __restrict__ mo,
                                                  const float* __restrict__ w,
                                                  const float* __restrict__ u,
                                                  float* __restrict__ out) {
    __shared__ float red[4];
    int r = blockIdx.x, tid = threadIdx.x;
    float v = mo[(size_t)r * 256 + tid];
    float ss = v * v;
    #pragma unroll
    for (int off = 32; off; off >>= 1) ss += __shfl_xor(ss, off, 64);
    if ((tid & 63) == 0) red[tid >> 6] = ss;
    __syncthreads();
    float tot = red[0] + red[1] + red[2] + red[3];
    float rs = rsqrtf(tot * (1.f / 256.f) + 1e-5f);
    out[(size_t)r * 256 + tid] = v * rs * w[tid] + u[(size_t)r * 256 + tid];
}

// ---------------- combine: comb = silu_w * (mo_f + flip_c(mo_b)) ----------------
__global__ __launch_bounds__(256) void k_comb(const float* __restrict__ wbuf,
                                              const float* __restrict__ mof,
                                              const float* __restrict__ mob,
                                              float* __restrict__ comb) {
    int r = blockIdx.x, tid = threadIdx.x;
    int b = r >> 10, c = r & 1023;
    int rb = (b << 10) | (1023 - c);
    comb[(size_t)r * 256 + tid] =
        wbuf[(size_t)r * 256 + tid] * (mof[(size_t)r * 256 + tid] + mob[(size_t)rb * 256 + tid]);
}

extern "C" void kernel_launch(void* const* d_in, const int* in_sizes, int n_in,
                              void* d_out, int out_size, void* d_ws, size_t ws_size,
                              hipStream_t stream) {
    const float* x          = (const float*)d_in[0];
    const float* W_in       = (const float*)d_in[1];
    const float* b_in       = (const float*)d_in[2];
    const float* W_wp       = (const float*)d_in[3];
    const float* b_wp       = (const float*)d_in[4];
    const float* W_fp       = (const float*)d_in[5];
    const float* b_fp       = (const float*)d_in[6];
    const float* W_bp       = (const float*)d_in[7];
    const float* b_bp       = (const float*)d_in[8];
    const float* W_out      = (const float*)d_in[9];
    const float* b_out      = (const float*)d_in[10];
    const float* norm_w_top = (const float*)d_in[11];
    const float* mamba_p[2][10];
    for (int p = 0; p < 2; ++p)
        for (int i = 0; i < 10; ++i)
            mamba_p[p][i] = (const float*)d_in[12 + p * 10 + i];

    float* ws = (float*)d_ws;
    float* xn    = ws + 0;                       // 524288
    float* ssm   = ws + 524288;                  // 1048576 (dead after step 4 -> reused below)
    float* uf    = ws + 1572864;                 // 1048576
    float* ub    = ws + 2621440;                 // 1048576
    float* mof   = ws + 3670016;                 // 1048576
    float* mob   = ws + 4718592;                 // 1048576
    float* xz    = ws + 5767168;                 // 4194304
    float* xconv = ws + 9961472;                 // 2097152
    float* dbl   = ws + 12058624;                // 196608
    float* dtb   = ws + 12255232;                // 2097152
    float* gated = ws + 14352384;                // 2097152 (end 16449536 floats = 62.7 MB)
    float* moraw = xz;                           // alias: xz dead after scan
    float* wbuf  = xz + 1048576;                 // alias
    float* comb  = xz + 2097152;                 // alias
    float* hfin  = ssm;                          // alias: ssm dead after uf/ub GEMMs (524288)
    float* Pfin  = ssm + 524288;                 // (524288)

    // 1. top rmsnorm
    k_rmsnorm128<<<NROW / 4, 256, 0, stream>>>(x, norm_w_top, xn);
    // 2. ssm_in = xn @ W_in^T + b_in        (M=4096,K=128,N=256)
    k_gemm<0><<<dim3(4, 64), 256, 0, stream>>>(xn, W_in, b_in, nullptr, ssm, NROW, 256, 128, 0);
    // 3. u_f = ssm @ W_fp^T + b_fp          (K=256,N=256)
    k_gemm<0><<<dim3(4, 64), 256, 0, stream>>>(ssm, W_fp, b_fp, nullptr, uf, NROW, 256, 256, 0);
    // 4. u_b = flip_c(ssm) @ W_bp^T + b_bp
    k_gemm<0><<<dim3(4, 64), 256, 0, stream>>>(ssm, W_bp, b_bp, nullptr, ub, NROW, 256, 256, 1);

    // 5/6. two mamba blocks (fwd on uf -> mof, bwd on ub -> mob)
    const float* u_of[2] = {uf, ub};
    float* mo_of[2] = {mof, mob};
    for (int p = 0; p < 2; ++p) {
        const float* in_w    = mamba_p[p][0];
        const float* conv_w  = mamba_p[p][1];
        const float* conv_b  = mamba_p[p][2];
        const float* xproj_w = mamba_p[p][3];
        const float* dt_w    = mamba_p[p][4];
        const float* dt_b    = mamba_p[p][5];
        const float* A_log   = mamba_p[p][6];
        const float* Dp      = mamba_p[p][7];
        const float* out_w   = mamba_p[p][8];
        const float* norm_w  = mamba_p[p][9];
        const float* u = u_of[p];

        // xz = u @ in_w^T                    (K=256,N=1024)
        k_gemm<0><<<dim3(16, 64), 256, 0, stream>>>(u, in_w, nullptr, nullptr, xz, NROW, 1024, 256, 0);
        // causal depthwise conv + silu
        k_conv<<<dim3(2, NROW), 256, 0, stream>>>(xz, conv_w, conv_b, xconv);
        // dbl = xconv @ xproj_w^T            (K=512,N=48)
        k_gemm<0><<<dim3(1, 64), 256, 0, stream>>>(xconv, xproj_w, nullptr, nullptr, dbl, NROW, 48, 512, 0);
        // dt = softplus(dbl[:, :16] @ dt_w^T + dt_b)
        k_dtproj<<<dim3(2, NROW), 256, 0, stream>>>(dbl, dt_w, dt_b, dtb);
        // chunked selective scan (3 passes)
        k_scan1<<<dim3(NCHUNK, 32, 4), 256, 0, stream>>>(dtb, xconv, dbl, A_log, hfin, Pfin);
        k_scan2<<<128, 256, 0, stream>>>(hfin, Pfin);
        k_scan3<<<dim3(NCHUNK, 32, 4), 256, 0, stream>>>(dtb, xconv, dbl, xz, A_log, Dp, Pfin, gated);
        // mo_raw = gated @ out_w^T           (K=512,N=256)
        k_gemm<0><<<dim3(4, 64), 256, 0, stream>>>(gated, out_w, nullptr, nullptr, moraw, NROW, 256, 512, 0);
        // postnorm: rmsnorm(mo_raw)*norm_w + u
        k_postnorm<<<NROW, 256, 0, stream>>>(moraw, norm_w, u, mo_of[p]);
    }

    // 7. wbuf = silu(xn @ W_wp^T + b_wp)     (K=128,N=256)
    k_gemm<1><<<dim3(4, 64), 256, 0, stream>>>(xn, W_wp, b_wp, nullptr, wbuf, NROW, 256, 128, 0);
    // 8. comb = wbuf * (mof + flip_c(mob))
    k_comb<<<NROW, 256, 0, stream>>>(wbuf, mof, mob, comb);
    // 9. out = comb @ W_out^T + b_out + x    (K=256,N=128)
    k_gemm<0><<<dim3(2, 64), 256, 0, stream>>>(comb, W_out, b_out, x, (float*)d_out, NROW, 128, 256, 0);
}

// Round 4
// 462.909 us; speedup vs baseline: 4.4350x; 1.2849x over previous
//
#include <hip/hip_runtime.h>
#include <math.h>

#define C_LEN 1024
#define NROW 4096   // B*C = 4*1024
#define NCHUNK 16
#define CHUNK 64    // C_LEN / NCHUNK

typedef __attribute__((ext_vector_type(8))) short short8;
typedef __attribute__((ext_vector_type(4))) float f32x4;

__device__ __forceinline__ float siluf(float x) { return x / (1.f + __expf(-x)); }

__device__ __forceinline__ unsigned short f2bf(float f) {
    unsigned u = __builtin_bit_cast(unsigned, f);
    unsigned r = (u + 0x7FFFu + ((u >> 16) & 1u)) >> 16;
    return (unsigned short)r;
}

// ---------------- rmsnorm over rows of width 128 (one wave per row) ----------------
__global__ __launch_bounds__(256) void k_rmsnorm128(const float* __restrict__ x,
                                                    const float* __restrict__ w,
                                                    float* __restrict__ out) {
    int wave = threadIdx.x >> 6, lane = threadIdx.x & 63;
    int row = blockIdx.x * 4 + wave;
    float2 v = ((const float2*)(x + (size_t)row * 128))[lane];
    float ss = v.x * v.x + v.y * v.y;
    #pragma unroll
    for (int off = 32; off; off >>= 1) ss += __shfl_xor(ss, off, 64);
    float rs = rsqrtf(ss * (1.f / 128.f) + 1e-5f);
    float2 wv = ((const float2*)w)[lane];
    float2 o; o.x = v.x * rs * wv.x; o.y = v.y * rs * wv.y;
    ((float2*)(out + (size_t)row * 128))[lane] = o;
}

// ---------------- bf16-MFMA GEMM: C[M,N] = act(A[M,K] @ W[N,K]^T + bias) (+resid) -----
// A, W fp32 in global; converted to bf16 during LDS staging. f32 accumulate via
// v_mfma_f32_16x16x32_bf16. Block tile 64x64, BK=32, 4 waves x (16m x 64n).
// flip!=0: logical row m reads physical A row with c -> C_LEN-1-c within its batch.
// Requires: M % 64 == 0, K % 32 == 0. N arbitrary (guarded).
template<int ACT>
__global__ __launch_bounds__(256) void k_gemm_mfma(const float* __restrict__ A,
                                                   const float* __restrict__ W,
                                                   const float* __restrict__ bias,
                                                   const float* __restrict__ resid,
                                                   float* __restrict__ Cout,
                                                   int M, int N, int K, int flip) {
    // LDS: 64 rows x 32 bf16, row stride padded to 40 ushorts (80 B) -> 2-way bank alias only
    __shared__ __align__(16) unsigned short As[64 * 40];
    __shared__ __align__(16) unsigned short Bs[64 * 40];
    int tid = threadIdx.x;
    int m0 = blockIdx.y * 64, n0 = blockIdx.x * 64;
    int w = tid >> 6, lane = tid & 63;
    int q = lane >> 4, ln = lane & 15;
    int srow = tid >> 2;        // 0..63 staging row
    int skq  = tid & 3;         // 0..3 staging k-quad (8 floats each)

    int mLog = m0 + srow;
    int mPhys = flip ? ((mLog & ~(C_LEN - 1)) | ((C_LEN - 1) - (mLog & (C_LEN - 1)))) : mLog;
    const float* pa = A + (size_t)mPhys * K + skq * 8;
    int nIdx = n0 + srow;
    const float* pw = W + (size_t)nIdx * K + skq * 8;
    bool nOK = (nIdx < N);

    f32x4 acc[4];
    #pragma unroll
    for (int j = 0; j < 4; ++j) acc[j] = (f32x4)(0.f);

    for (int k0 = 0; k0 < K; k0 += 32) {
        // stage A
        float4 a0 = *(const float4*)(pa);
        float4 a1 = *(const float4*)(pa + 4);
        short8 av;
        av[0] = (short)f2bf(a0.x); av[1] = (short)f2bf(a0.y);
        av[2] = (short)f2bf(a0.z); av[3] = (short)f2bf(a0.w);
        av[4] = (short)f2bf(a1.x); av[5] = (short)f2bf(a1.y);
        av[6] = (short)f2bf(a1.z); av[7] = (short)f2bf(a1.w);
        *(short8*)&As[srow * 40 + skq * 8] = av;
        // stage B (W rows; zero-pad past N)
        short8 bv = (short8)(0);
        if (nOK) {
            float4 b0 = *(const float4*)(pw);
            float4 b1 = *(const float4*)(pw + 4);
            bv[0] = (short)f2bf(b0.x); bv[1] = (short)f2bf(b0.y);
            bv[2] = (short)f2bf(b0.z); bv[3] = (short)f2bf(b0.w);
            bv[4] = (short)f2bf(b1.x); bv[5] = (short)f2bf(b1.y);
            bv[6] = (short)f2bf(b1.z); bv[7] = (short)f2bf(b1.w);
        }
        *(short8*)&Bs[srow * 40 + skq * 8] = bv;
        pa += 32; pw += 32;
        __syncthreads();

        // fragments + MFMA: wave w covers rows w*16..w*16+15, all 64 cols
        short8 af = *(const short8*)&As[(w * 16 + ln) * 40 + q * 8];
        #pragma unroll
        for (int j = 0; j < 4; ++j) {
            short8 bf = *(const short8*)&Bs[(j * 16 + ln) * 40 + q * 8];
            acc[j] = __builtin_amdgcn_mfma_f32_16x16x32_bf16(af, bf, acc[j], 0, 0, 0);
        }
        __syncthreads();
    }

    // epilogue: C/D layout col = lane&15, row = q*4 + reg
    #pragma unroll
    for (int j = 0; j < 4; ++j) {
        int nn = n0 + j * 16 + ln;
        if (nn < N) {
            float bsv = bias ? bias[nn] : 0.f;
            #pragma unroll
            for (int r = 0; r < 4; ++r) {
                int m = m0 + w * 16 + q * 4 + r;
                float v = acc[j][r] + bsv;
                if (ACT == 1) v = siluf(v);
                if (resid) v += resid[(size_t)m * N + nn];
                Cout[(size_t)m * N + nn] = v;
            }
        }
    }
}

// ---------------- causal depthwise conv (K=4) + silu: xz[:, :512] -> xconv ----------------
__global__ __launch_bounds__(256) void k_conv(const float* __restrict__ xz,
                                              const float* __restrict__ cw,
                                              const float* __restrict__ cb,
                                              float* __restrict__ xconv) {
    int d = blockIdx.x * 256 + threadIdx.x;   // 0..511
    int bc = blockIdx.y;                      // 0..4095
    int b = bc >> 10, c = bc & 1023;
    float acc = cb[d];
    const float* base = xz + (size_t)(b * C_LEN) * 1024 + d;
    #pragma unroll
    for (int k = 0; k < 4; ++k) {
        int cc = c - 3 + k;
        if (cc >= 0) acc = fmaf(cw[d * 4 + k], base[(size_t)cc * 1024], acc);
    }
    xconv[(size_t)bc * 512 + d] = siluf(acc);
}

// ---------------- dt projection: dt = softplus(dbl[:, :16] @ dt_w^T + dt_b) ----------------
__global__ __launch_bounds__(256) void k_dtproj(const float* __restrict__ dbl,
                                                const float* __restrict__ dtw,
                                                const float* __restrict__ dtb,
                                                float* __restrict__ dt) {
    int d = blockIdx.x * 256 + threadIdx.x;   // 0..511
    int r = blockIdx.y;                       // 0..4095
    float s = dtb[d];
    const float* row = dbl + (size_t)r * 48;
    #pragma unroll
    for (int j = 0; j < 16; ++j) s = fmaf(row[j], dtw[d * 16 + j], s);
    float sp = fmaxf(s, 0.f) + log1pf(__expf(-fabsf(s)));
    dt[(size_t)r * 512 + d] = sp;
}

// ---------------- chunked selective scan, pass 1: local scan per chunk ----------------
__global__ __launch_bounds__(256) void k_scan1(const float* __restrict__ dt,
                                               const float* __restrict__ xconv,
                                               const float* __restrict__ dbl,
                                               const float* __restrict__ A_log,
                                               float* __restrict__ hfin,
                                               float* __restrict__ Pfin) {
    int tid = threadIdx.x;
    int n = tid & 15, dl = tid >> 4;
    int k = blockIdx.x, dg = blockIdx.y, b = blockIdx.z;
    int d = dg * 16 + dl;
    float Acoef = -__expf(A_log[d * 16 + n]);
    int c0 = k * CHUNK;
    size_t r0 = (size_t)(b * C_LEN + c0);
    const float* pdt = dt + r0 * 512 + d;
    const float* pxv = xconv + r0 * 512 + d;
    const float* pB  = dbl + r0 * 48 + 16 + n;
    float h = 0.f, sdt = 0.f;
    #pragma unroll 8
    for (int c = 0; c < CHUNK; ++c) {
        float dtv = *pdt;
        float xv  = *pxv;
        float Bv  = *pB;
        float a = __expf(dtv * Acoef);
        h = fmaf(a, h, dtv * xv * Bv);
        sdt += dtv;
        pdt += 512; pxv += 512; pB += 48;
    }
    size_t idx = ((size_t)(b * NCHUNK + k) * 512 + d) * 16 + n;
    hfin[idx] = h;
    Pfin[idx] = __expf(Acoef * sdt);
}

// ---------------- pass 2: sequential combine over chunks; writes carry-in into Pfin --------
__global__ __launch_bounds__(256) void k_scan2(const float* __restrict__ hfin,
                                               float* __restrict__ Pfin) {
    int t = blockIdx.x * 256 + threadIdx.x;   // (b*512+d)*16+n
    int b = t >> 13;
    int dn = t & 8191;
    float carry = 0.f;
    #pragma unroll
    for (int k = 0; k < NCHUNK; ++k) {
        size_t idx = (size_t)(b * NCHUNK + k) * 8192 + dn;
        float p = Pfin[idx];
        float hf = hfin[idx];
        Pfin[idx] = carry;                    // carry-in for chunk k
        carry = fmaf(p, carry, hf);
    }
}

// ---------------- pass 3: replay chunk with carry-in; emit y + D skip + z gate ------------
__global__ __launch_bounds__(256) void k_scan3(const float* __restrict__ dt,
                                               const float* __restrict__ xconv,
                                               const float* __restrict__ dbl,
                                               const float* __restrict__ xz,
                                               const float* __restrict__ A_log,
                                               const float* __restrict__ Dp,
                                               const float* __restrict__ carryArr,
                                               float* __restrict__ gated) {
    int tid = threadIdx.x;
    int n = tid & 15, dl = tid >> 4;
    int k = blockIdx.x, dg = blockIdx.y, b = blockIdx.z;
    int d = dg * 16 + dl;
    float Acoef = -__expf(A_log[d * 16 + n]);
    float Dd = Dp[d];
    float h = carryArr[((size_t)(b * NCHUNK + k) * 512 + d) * 16 + n];
    int c0 = k * CHUNK;
    size_t r0 = (size_t)(b * C_LEN + c0);
    const float* pdt = dt + r0 * 512 + d;
    const float* pxv = xconv + r0 * 512 + d;
    const float* pB  = dbl + r0 * 48 + 16 + n;
    const float* pC  = dbl + r0 * 48 + 32 + n;
    const float* pz  = xz + r0 * 1024 + 512 + d;
    float* pg        = gated + r0 * 512 + d;
    #pragma unroll 4
    for (int c = 0; c < CHUNK; ++c) {
        float dtv = *pdt;
        float xv  = *pxv;
        float Bv  = *pB;
        float Cv  = *pC;
        h = fmaf(__expf(dtv * Acoef), h, dtv * xv * Bv);
        float contrib = h * Cv;
        #pragma unroll
        for (int off = 8; off; off >>= 1) contrib += __shfl_xor(contrib, off, 16);
        if (n == 0) {
            float y = contrib + xv * Dd;
            float zv = *pz;
            *pg = y * siluf(zv);
        }
        pdt += 512; pxv += 512; pB += 48; pC += 48; pz += 1024; pg += 512;
    }
}

// ---------------- postnorm: rmsnorm(mo, w) + u, width 256 ----------------
__global__ __launch_bounds__(256) void k_postnorm(const float* __restrict__ mo,
                                                  const float* __restrict__ w,
                                                  const float* __restrict__ u,
                                                  float* __restrict__ out) {
    __shared__ float red[4];
    int r = blockIdx.x, tid = threadIdx.x;
    float v = mo[(size_t)r * 256 + tid];
    float ss = v * v;
    #pragma unroll
    for (int off = 32; off; off >>= 1) ss += __shfl_xor(ss, off, 64);
    if ((tid & 63) == 0) red[tid >> 6] = ss;
    __syncthreads();
    float tot = red[0] + red[1] + red[2] + red[3];
    float rs = rsqrtf(tot * (1.f / 256.f) + 1e-5f);
    out[(size_t)r * 256 + tid] = v * rs * w[tid] + u[(size_t)r * 256 + tid];
}

// ---------------- combine: comb = silu_w * (mo_f + flip_c(mo_b)) ----------------
__global__ __launch_bounds__(256) void k_comb(const float* __restrict__ wbuf,
                                              const float* __restrict__ mof,
                                              const float* __restrict__ mob,
                                              float* __restrict__ comb) {
    int r = blockIdx.x, tid = threadIdx.x;
    int b = r >> 10, c = r & 1023;
    int rb = (b << 10) | (1023 - c);
    comb[(size_t)r * 256 + tid] =
        wbuf[(size_t)r * 256 + tid] * (mof[(size_t)r * 256 + tid] + mob[(size_t)rb * 256 + tid]);
}

extern "C" void kernel_launch(void* const* d_in, const int* in_sizes, int n_in,
                              void* d_out, int out_size, void* d_ws, size_t ws_size,
                              hipStream_t stream) {
    const float* x          = (const float*)d_in[0];
    const float* W_in       = (const float*)d_in[1];
    const float* b_in       = (const float*)d_in[2];
    const float* W_wp       = (const float*)d_in[3];
    const float* b_wp       = (const float*)d_in[4];
    const float* W_fp       = (const float*)d_in[5];
    const float* b_fp       = (const float*)d_in[6];
    const float* W_bp       = (const float*)d_in[7];
    const float* b_bp       = (const float*)d_in[8];
    const float* W_out      = (const float*)d_in[9];
    const float* b_out      = (const float*)d_in[10];
    const float* norm_w_top = (const float*)d_in[11];
    const float* mamba_p[2][10];
    for (int p = 0; p < 2; ++p)
        for (int i = 0; i < 10; ++i)
            mamba_p[p][i] = (const float*)d_in[12 + p * 10 + i];

    float* ws = (float*)d_ws;
    float* xn    = ws + 0;                       // 524288
    float* ssm   = ws + 524288;                  // 1048576 (dead after step 4 -> reused below)
    float* uf    = ws + 1572864;                 // 1048576
    float* ub    = ws + 2621440;                 // 1048576
    float* mof   = ws + 3670016;                 // 1048576
    float* mob   = ws + 4718592;                 // 1048576
    float* xz    = ws + 5767168;                 // 4194304
    float* xconv = ws + 9961472;                 // 2097152
    float* dbl   = ws + 12058624;                // 196608
    float* dtb   = ws + 12255232;                // 2097152
    float* gated = ws + 14352384;                // 2097152 (end 16449536 floats = 62.7 MB)
    float* moraw = xz;                           // alias: xz dead after scan
    float* wbuf  = xz + 1048576;                 // alias
    float* comb  = xz + 2097152;                 // alias
    float* hfin  = ssm;                          // alias: ssm dead after uf/ub GEMMs (524288)
    float* Pfin  = ssm + 524288;                 // (524288)

    // 1. top rmsnorm
    k_rmsnorm128<<<NROW / 4, 256, 0, stream>>>(x, norm_w_top, xn);
    // 2. ssm_in = xn @ W_in^T + b_in        (M=4096,K=128,N=256)
    k_gemm_mfma<0><<<dim3(4, 64), 256, 0, stream>>>(xn, W_in, b_in, nullptr, ssm, NROW, 256, 128, 0);
    // 3. u_f = ssm @ W_fp^T + b_fp          (K=256,N=256)
    k_gemm_mfma<0><<<dim3(4, 64), 256, 0, stream>>>(ssm, W_fp, b_fp, nullptr, uf, NROW, 256, 256, 0);
    // 4. u_b = flip_c(ssm) @ W_bp^T + b_bp
    k_gemm_mfma<0><<<dim3(4, 64), 256, 0, stream>>>(ssm, W_bp, b_bp, nullptr, ub, NROW, 256, 256, 1);

    // 5/6. two mamba blocks (fwd on uf -> mof, bwd on ub -> mob)
    const float* u_of[2] = {uf, ub};
    float* mo_of[2] = {mof, mob};
    for (int p = 0; p < 2; ++p) {
        const float* in_w    = mamba_p[p][0];
        const float* conv_w  = mamba_p[p][1];
        const float* conv_b  = mamba_p[p][2];
        const float* xproj_w = mamba_p[p][3];
        const float* dt_w    = mamba_p[p][4];
        const float* dt_b    = mamba_p[p][5];
        const float* A_log   = mamba_p[p][6];
        const float* Dp      = mamba_p[p][7];
        const float* out_w   = mamba_p[p][8];
        const float* norm_w  = mamba_p[p][9];
        const float* u = u_of[p];

        // xz = u @ in_w^T                    (K=256,N=1024)
        k_gemm_mfma<0><<<dim3(16, 64), 256, 0, stream>>>(u, in_w, nullptr, nullptr, xz, NROW, 1024, 256, 0);
        // causal depthwise conv + silu
        k_conv<<<dim3(2, NROW), 256, 0, stream>>>(xz, conv_w, conv_b, xconv);
        // dbl = xconv @ xproj_w^T            (K=512,N=48)
        k_gemm_mfma<0><<<dim3(1, 64), 256, 0, stream>>>(xconv, xproj_w, nullptr, nullptr, dbl, NROW, 48, 512, 0);
        // dt = softplus(dbl[:, :16] @ dt_w^T + dt_b)
        k_dtproj<<<dim3(2, NROW), 256, 0, stream>>>(dbl, dt_w, dt_b, dtb);
        // chunked selective scan (3 passes)
        k_scan1<<<dim3(NCHUNK, 32, 4), 256, 0, stream>>>(dtb, xconv, dbl, A_log, hfin, Pfin);
        k_scan2<<<128, 256, 0, stream>>>(hfin, Pfin);
        k_scan3<<<dim3(NCHUNK, 32, 4), 256, 0, stream>>>(dtb, xconv, dbl, xz, A_log, Dp, Pfin, gated);
        // mo_raw = gated @ out_w^T           (K=512,N=256)
        k_gemm_mfma<0><<<dim3(4, 64), 256, 0, stream>>>(gated, out_w, nullptr, nullptr, moraw, NROW, 256, 512, 0);
        // postnorm: rmsnorm(mo_raw)*norm_w + u
        k_postnorm<<<NROW, 256, 0, stream>>>(moraw, norm_w, u, mo_of[p]);
    }

    // 7. wbuf = silu(xn @ W_wp^T + b_wp)     (K=128,N=256)
    k_gemm_mfma<1><<<dim3(4, 64), 256, 0, stream>>>(xn, W_wp, b_wp, nullptr, wbuf, NROW, 256, 128, 0);
    // 8. comb = wbuf * (mof + flip_c(mob))
    k_comb<<<NROW, 256, 0, stream>>>(wbuf, mof, mob, comb);
    // 9. out = comb @ W_out^T + b_out + x    (K=256,N=128)
    k_gemm_mfma<0><<<dim3(2, 64), 256, 0, stream>>>(comb, W_out, b_out, x, (float*)d_out, NROW, 128, 256, 0);
}

// Round 5
// 444.138 us; speedup vs baseline: 4.6225x; 1.0423x over previous
//
#include <hip/hip_runtime.h>
#include <math.h>

#define C_LEN 1024
#define NROW 4096   // B*C = 4*1024
#define NCHUNK 32
#define CHUNK 32    // C_LEN / NCHUNK

typedef __attribute__((ext_vector_type(8))) short short8;
typedef __attribute__((ext_vector_type(4))) float f32x4;

__device__ __forceinline__ float siluf(float x) { return x / (1.f + __expf(-x)); }

__device__ __forceinline__ unsigned short f2bf(float f) {
    unsigned u = __builtin_bit_cast(unsigned, f);
    unsigned r = (u + 0x7FFFu + ((u >> 16) & 1u)) >> 16;
    return (unsigned short)r;
}

// ---------------- rmsnorm over rows of width 128 (one wave per row) ----------------
__global__ __launch_bounds__(256) void k_rmsnorm128(const float* __restrict__ x,
                                                    const float* __restrict__ w,
                                                    float* __restrict__ out) {
    int wave = threadIdx.x >> 6, lane = threadIdx.x & 63;
    int row = blockIdx.x * 4 + wave;
    float2 v = ((const float2*)(x + (size_t)row * 128))[lane];
    float ss = v.x * v.x + v.y * v.y;
    #pragma unroll
    for (int off = 32; off; off >>= 1) ss += __shfl_xor(ss, off, 64);
    float rs = rsqrtf(ss * (1.f / 128.f) + 1e-5f);
    float2 wv = ((const float2*)w)[lane];
    float2 o; o.x = v.x * rs * wv.x; o.y = v.y * rs * wv.y;
    ((float2*)(out + (size_t)row * 128))[lane] = o;
}

// ---------------- bf16-MFMA GEMM: C[M,N] = act(A[M,K] @ W[N,K]^T + bias) (+resid) -----
template<int ACT>
__global__ __launch_bounds__(256) void k_gemm_mfma(const float* __restrict__ A,
                                                   const float* __restrict__ W,
                                                   const float* __restrict__ bias,
                                                   const float* __restrict__ resid,
                                                   float* __restrict__ Cout,
                                                   int M, int N, int K, int flip) {
    __shared__ __align__(16) unsigned short As[64 * 40];
    __shared__ __align__(16) unsigned short Bs[64 * 40];
    int tid = threadIdx.x;
    int m0 = blockIdx.y * 64, n0 = blockIdx.x * 64;
    int w = tid >> 6, lane = tid & 63;
    int q = lane >> 4, ln = lane & 15;
    int srow = tid >> 2;        // 0..63 staging row
    int skq  = tid & 3;         // 0..3 staging k-quad (8 floats each)

    int mLog = m0 + srow;
    int mPhys = flip ? ((mLog & ~(C_LEN - 1)) | ((C_LEN - 1) - (mLog & (C_LEN - 1)))) : mLog;
    const float* pa = A + (size_t)mPhys * K + skq * 8;
    int nIdx = n0 + srow;
    const float* pw = W + (size_t)nIdx * K + skq * 8;
    bool nOK = (nIdx < N);

    f32x4 acc[4];
    #pragma unroll
    for (int j = 0; j < 4; ++j) acc[j] = (f32x4)(0.f);

    for (int k0 = 0; k0 < K; k0 += 32) {
        float4 a0 = *(const float4*)(pa);
        float4 a1 = *(const float4*)(pa + 4);
        short8 av;
        av[0] = (short)f2bf(a0.x); av[1] = (short)f2bf(a0.y);
        av[2] = (short)f2bf(a0.z); av[3] = (short)f2bf(a0.w);
        av[4] = (short)f2bf(a1.x); av[5] = (short)f2bf(a1.y);
        av[6] = (short)f2bf(a1.z); av[7] = (short)f2bf(a1.w);
        *(short8*)&As[srow * 40 + skq * 8] = av;
        short8 bv = (short8)(0);
        if (nOK) {
            float4 b0 = *(const float4*)(pw);
            float4 b1 = *(const float4*)(pw + 4);
            bv[0] = (short)f2bf(b0.x); bv[1] = (short)f2bf(b0.y);
            bv[2] = (short)f2bf(b0.z); bv[3] = (short)f2bf(b0.w);
            bv[4] = (short)f2bf(b1.x); bv[5] = (short)f2bf(b1.y);
            bv[6] = (short)f2bf(b1.z); bv[7] = (short)f2bf(b1.w);
        }
        *(short8*)&Bs[srow * 40 + skq * 8] = bv;
        pa += 32; pw += 32;
        __syncthreads();

        short8 af = *(const short8*)&As[(w * 16 + ln) * 40 + q * 8];
        #pragma unroll
        for (int j = 0; j < 4; ++j) {
            short8 bf = *(const short8*)&Bs[(j * 16 + ln) * 40 + q * 8];
            acc[j] = __builtin_amdgcn_mfma_f32_16x16x32_bf16(af, bf, acc[j], 0, 0, 0);
        }
        __syncthreads();
    }

    #pragma unroll
    for (int j = 0; j < 4; ++j) {
        int nn = n0 + j * 16 + ln;
        if (nn < N) {
            float bsv = bias ? bias[nn] : 0.f;
            #pragma unroll
            for (int r = 0; r < 4; ++r) {
                int m = m0 + w * 16 + q * 4 + r;
                float v = acc[j][r] + bsv;
                if (ACT == 1) v = siluf(v);
                if (resid) v += resid[(size_t)m * N + nn];
                Cout[(size_t)m * N + nn] = v;
            }
        }
    }
}

// ---------------- causal depthwise conv (K=4) + silu: xz[:, :512] -> xconv ----------------
__global__ __launch_bounds__(256) void k_conv(const float* __restrict__ xz,
                                              const float* __restrict__ cw,
                                              const float* __restrict__ cb,
                                              float* __restrict__ xconv) {
    int d = blockIdx.x * 256 + threadIdx.x;   // 0..511
    int bc = blockIdx.y;                      // 0..4095
    int b = bc >> 10, c = bc & 1023;
    float acc = cb[d];
    const float* base = xz + (size_t)(b * C_LEN) * 1024 + d;
    #pragma unroll
    for (int k = 0; k < 4; ++k) {
        int cc = c - 3 + k;
        if (cc >= 0) acc = fmaf(cw[d * 4 + k], base[(size_t)cc * 1024], acc);
    }
    xconv[(size_t)bc * 512 + d] = siluf(acc);
}

// ---------------- dt projection: dt = softplus(dbl[:, :16] @ dt_w^T + dt_b) ----------------
__global__ __launch_bounds__(256) void k_dtproj(const float* __restrict__ dbl,
                                                const float* __restrict__ dtw,
                                                const float* __restrict__ dtb,
                                                float* __restrict__ dt) {
    int d = blockIdx.x * 256 + threadIdx.x;   // 0..511
    int r = blockIdx.y;                       // 0..4095
    float s = dtb[d];
    const float* row = dbl + (size_t)r * 48;
    #pragma unroll
    for (int j = 0; j < 16; ++j) s = fmaf(row[j], dtw[d * 16 + j], s);
    float sp = fmaxf(s, 0.f) + log1pf(__expf(-fabsf(s)));
    dt[(size_t)r * 512 + d] = sp;
}

// ---------------- chunked selective scan, pass 1: local scan per chunk ----------------
// 8 n-states per lane, 2 lanes per d. block 256 = 128 d x 2 nh.
// grid = (NCHUNK, 4 dgroups, 4 b). emits hfin/Pfin [b][k][d][n].
__global__ __launch_bounds__(256) void k_scan1(const float* __restrict__ dt,
                                               const float* __restrict__ xconv,
                                               const float* __restrict__ dbl,
                                               const float* __restrict__ A_log,
                                               float* __restrict__ hfin,
                                               float* __restrict__ Pfin) {
    int tid = threadIdx.x;
    int nh = tid & 1, dl = tid >> 1;          // nh: which 8-state half; dl: 0..127
    int k = blockIdx.x, dg = blockIdx.y, b = blockIdx.z;
    int d = dg * 128 + dl;
    float4 al0 = *(const float4*)&A_log[d * 16 + nh * 8];
    float4 al1 = *(const float4*)&A_log[d * 16 + nh * 8 + 4];
    float Ac[8] = {-__expf(al0.x), -__expf(al0.y), -__expf(al0.z), -__expf(al0.w),
                   -__expf(al1.x), -__expf(al1.y), -__expf(al1.z), -__expf(al1.w)};
    size_t r0 = (size_t)(b * C_LEN + k * CHUNK);
    const float* pdt = dt + r0 * 512 + d;
    const float* pxv = xconv + r0 * 512 + d;
    const float* pB  = dbl + r0 * 48 + 16 + nh * 8;
    float h[8] = {0.f, 0.f, 0.f, 0.f, 0.f, 0.f, 0.f, 0.f};
    float sdt = 0.f;
    #pragma unroll 8
    for (int c = 0; c < CHUNK; ++c) {
        float dtv = *pdt;
        float xv  = *pxv;
        float4 B0 = *(const float4*)pB;
        float4 B1 = *(const float4*)(pB + 4);
        float dx = dtv * xv;
        float Bv[8] = {B0.x, B0.y, B0.z, B0.w, B1.x, B1.y, B1.z, B1.w};
        #pragma unroll
        for (int j = 0; j < 8; ++j)
            h[j] = fmaf(__expf(dtv * Ac[j]), h[j], dx * Bv[j]);
        sdt += dtv;
        pdt += 512; pxv += 512; pB += 48;
    }
    size_t idx = ((size_t)(b * NCHUNK + k) * 512 + d) * 16 + nh * 8;
    *(float4*)&hfin[idx]     = make_float4(h[0], h[1], h[2], h[3]);
    *(float4*)&hfin[idx + 4] = make_float4(h[4], h[5], h[6], h[7]);
    *(float4*)&Pfin[idx]     = make_float4(__expf(Ac[0] * sdt), __expf(Ac[1] * sdt),
                                           __expf(Ac[2] * sdt), __expf(Ac[3] * sdt));
    *(float4*)&Pfin[idx + 4] = make_float4(__expf(Ac[4] * sdt), __expf(Ac[5] * sdt),
                                           __expf(Ac[6] * sdt), __expf(Ac[7] * sdt));
}

// ---------------- pass 2: sequential combine over chunks; writes carry-in into Pfin --------
__global__ __launch_bounds__(256) void k_scan2(const float* __restrict__ hfin,
                                               float* __restrict__ Pfin) {
    int t = blockIdx.x * 256 + threadIdx.x;   // (b*512+d)*16+n
    int b = t >> 13;
    int dn = t & 8191;
    float carry = 0.f;
    #pragma unroll
    for (int k = 0; k < NCHUNK; ++k) {
        size_t idx = (size_t)(b * NCHUNK + k) * 8192 + dn;
        float p = Pfin[idx];
        float hf = hfin[idx];
        Pfin[idx] = carry;                    // carry-in for chunk k
        carry = fmaf(p, carry, hf);
    }
}

// ---------------- pass 3: replay chunk with carry-in; emit y + D skip + z gate ------------
__global__ __launch_bounds__(256) void k_scan3(const float* __restrict__ dt,
                                               const float* __restrict__ xconv,
                                               const float* __restrict__ dbl,
                                               const float* __restrict__ xz,
                                               const float* __restrict__ A_log,
                                               const float* __restrict__ Dp,
                                               const float* __restrict__ carryArr,
                                               float* __restrict__ gated) {
    int tid = threadIdx.x;
    int nh = tid & 1, dl = tid >> 1;
    int k = blockIdx.x, dg = blockIdx.y, b = blockIdx.z;
    int d = dg * 128 + dl;
    float4 al0 = *(const float4*)&A_log[d * 16 + nh * 8];
    float4 al1 = *(const float4*)&A_log[d * 16 + nh * 8 + 4];
    float Ac[8] = {-__expf(al0.x), -__expf(al0.y), -__expf(al0.z), -__expf(al0.w),
                   -__expf(al1.x), -__expf(al1.y), -__expf(al1.z), -__expf(al1.w)};
    float Dd = Dp[d];
    size_t idx = ((size_t)(b * NCHUNK + k) * 512 + d) * 16 + nh * 8;
    float4 h0 = *(const float4*)&carryArr[idx];
    float4 h1 = *(const float4*)&carryArr[idx + 4];
    float h[8] = {h0.x, h0.y, h0.z, h0.w, h1.x, h1.y, h1.z, h1.w};
    size_t r0 = (size_t)(b * C_LEN + k * CHUNK);
    const float* pdt = dt + r0 * 512 + d;
    const float* pxv = xconv + r0 * 512 + d;
    const float* pB  = dbl + r0 * 48 + 16 + nh * 8;
    const float* pC  = dbl + r0 * 48 + 32 + nh * 8;
    const float* pz  = xz + r0 * 1024 + 512 + d;
    float* pg        = gated + r0 * 512 + d;
    #pragma unroll 4
    for (int c = 0; c < CHUNK; ++c) {
        float dtv = *pdt;
        float xv  = *pxv;
        float4 B0 = *(const float4*)pB;
        float4 B1 = *(const float4*)(pB + 4);
        float4 C0 = *(const float4*)pC;
        float4 C1 = *(const float4*)(pC + 4);
        float dx = dtv * xv;
        float Bv[8] = {B0.x, B0.y, B0.z, B0.w, B1.x, B1.y, B1.z, B1.w};
        float Cv[8] = {C0.x, C0.y, C0.z, C0.w, C1.x, C1.y, C1.z, C1.w};
        float contrib = 0.f;
        #pragma unroll
        for (int j = 0; j < 8; ++j) {
            h[j] = fmaf(__expf(dtv * Ac[j]), h[j], dx * Bv[j]);
            contrib = fmaf(h[j], Cv[j], contrib);
        }
        contrib += __shfl_xor(contrib, 1, 64);
        if (nh == 0) {
            float y = contrib + xv * Dd;
            float zv = *pz;
            *pg = y * siluf(zv);
        }
        pdt += 512; pxv += 512; pB += 48; pC += 48; pz += 1024; pg += 512;
    }
}

// ---------------- postnorm: rmsnorm(mo, w) + u, width 256 ----------------
__global__ __launch_bounds__(256) void k_postnorm(const float* __restrict__ mo,
                                                  const float* __restrict__ w,
                                                  const float* __restrict__ u,
                                                  float* __restrict__ out) {
    __shared__ float red[4];
    int r = blockIdx.x, tid = threadIdx.x;
    float v = mo[(size_t)r * 256 + tid];
    float ss = v * v;
    #pragma unroll
    for (int off = 32; off; off >>= 1) ss += __shfl_xor(ss, off, 64);
    if ((tid & 63) == 0) red[tid >> 6] = ss;
    __syncthreads();
    float tot = red[0] + red[1] + red[2] + red[3];
    float rs = rsqrtf(tot * (1.f / 256.f) + 1e-5f);
    out[(size_t)r * 256 + tid] = v * rs * w[tid] + u[(size_t)r * 256 + tid];
}

// ---------------- combine: comb = silu_w * (mo_f + flip_c(mo_b)) ----------------
__global__ __launch_bounds__(256) void k_comb(const float* __restrict__ wbuf,
                                              const float* __restrict__ mof,
                                              const float* __restrict__ mob,
                                              float* __restrict__ comb) {
    int r = blockIdx.x, tid = threadIdx.x;
    int b = r >> 10, c = r & 1023;
    int rb = (b << 10) | (1023 - c);
    comb[(size_t)r * 256 + tid] =
        wbuf[(size_t)r * 256 + tid] * (mof[(size_t)r * 256 + tid] + mob[(size_t)rb * 256 + tid]);
}

extern "C" void kernel_launch(void* const* d_in, const int* in_sizes, int n_in,
                              void* d_out, int out_size, void* d_ws, size_t ws_size,
                              hipStream_t stream) {
    const float* x          = (const float*)d_in[0];
    const float* W_in       = (const float*)d_in[1];
    const float* b_in       = (const float*)d_in[2];
    const float* W_wp       = (const float*)d_in[3];
    const float* b_wp       = (const float*)d_in[4];
    const float* W_fp       = (const float*)d_in[5];
    const float* b_fp       = (const float*)d_in[6];
    const float* W_bp       = (const float*)d_in[7];
    const float* b_bp       = (const float*)d_in[8];
    const float* W_out      = (const float*)d_in[9];
    const float* b_out      = (const float*)d_in[10];
    const float* norm_w_top = (const float*)d_in[11];
    const float* mamba_p[2][10];
    for (int p = 0; p < 2; ++p)
        for (int i = 0; i < 10; ++i)
            mamba_p[p][i] = (const float*)d_in[12 + p * 10 + i];

    float* ws = (float*)d_ws;
    float* xn    = ws + 0;                       // 524288
    float* ssm   = ws + 524288;                  // 1048576 (dead after step 4 -> hfin)
    float* uf    = ws + 1572864;                 // 1048576
    float* ub    = ws + 2621440;                 // 1048576
    float* mof   = ws + 3670016;                 // 1048576
    float* mob   = ws + 4718592;                 // 1048576 (free during scans -> Pfin)
    float* xz    = ws + 5767168;                 // 4194304
    float* xconv = ws + 9961472;                 // 2097152
    float* dbl   = ws + 12058624;                // 196608
    float* dtb   = ws + 12255232;                // 2097152
    float* gated = ws + 14352384;                // 2097152 (end 16449536 floats = 62.7 MB)
    float* moraw = xz;                           // alias: xz dead after scan
    float* wbuf  = xz + 1048576;                 // alias
    float* comb  = xz + 2097152;                 // alias
    float* hfin  = ssm;                          // 1048576 = 4*32*512*16 exactly
    float* Pfin  = mob;                          // mob written only by postnorm AFTER scan3

    // 1. top rmsnorm
    k_rmsnorm128<<<NROW / 4, 256, 0, stream>>>(x, norm_w_top, xn);
    // 2. ssm_in = xn @ W_in^T + b_in        (M=4096,K=128,N=256)
    k_gemm_mfma<0><<<dim3(4, 64), 256, 0, stream>>>(xn, W_in, b_in, nullptr, ssm, NROW, 256, 128, 0);
    // 3. u_f = ssm @ W_fp^T + b_fp          (K=256,N=256)
    k_gemm_mfma<0><<<dim3(4, 64), 256, 0, stream>>>(ssm, W_fp, b_fp, nullptr, uf, NROW, 256, 256, 0);
    // 4. u_b = flip_c(ssm) @ W_bp^T + b_bp
    k_gemm_mfma<0><<<dim3(4, 64), 256, 0, stream>>>(ssm, W_bp, b_bp, nullptr, ub, NROW, 256, 256, 1);

    // 5/6. two mamba blocks (fwd on uf -> mof, bwd on ub -> mob)
    const float* u_of[2] = {uf, ub};
    float* mo_of[2] = {mof, mob};
    for (int p = 0; p < 2; ++p) {
        const float* in_w    = mamba_p[p][0];
        const float* conv_w  = mamba_p[p][1];
        const float* conv_b  = mamba_p[p][2];
        const float* xproj_w = mamba_p[p][3];
        const float* dt_w    = mamba_p[p][4];
        const float* dt_b    = mamba_p[p][5];
        const float* A_log   = mamba_p[p][6];
        const float* Dp      = mamba_p[p][7];
        const float* out_w   = mamba_p[p][8];
        const float* norm_w  = mamba_p[p][9];
        const float* u = u_of[p];

        // xz = u @ in_w^T                    (K=256,N=1024)
        k_gemm_mfma<0><<<dim3(16, 64), 256, 0, stream>>>(u, in_w, nullptr, nullptr, xz, NROW, 1024, 256, 0);
        // causal depthwise conv + silu
        k_conv<<<dim3(2, NROW), 256, 0, stream>>>(xz, conv_w, conv_b, xconv);
        // dbl = xconv @ xproj_w^T            (K=512,N=48)
        k_gemm_mfma<0><<<dim3(1, 64), 256, 0, stream>>>(xconv, xproj_w, nullptr, nullptr, dbl, NROW, 48, 512, 0);
        // dt = softplus(dbl[:, :16] @ dt_w^T + dt_b)
        k_dtproj<<<dim3(2, NROW), 256, 0, stream>>>(dbl, dt_w, dt_b, dtb);
        // chunked selective scan (3 passes)
        k_scan1<<<dim3(NCHUNK, 4, 4), 256, 0, stream>>>(dtb, xconv, dbl, A_log, hfin, Pfin);
        k_scan2<<<128, 256, 0, stream>>>(hfin, Pfin);
        k_scan3<<<dim3(NCHUNK, 4, 4), 256, 0, stream>>>(dtb, xconv, dbl, xz, A_log, Dp, Pfin, gated);
        // mo_raw = gated @ out_w^T           (K=512,N=256)
        k_gemm_mfma<0><<<dim3(4, 64), 256, 0, stream>>>(gated, out_w, nullptr, nullptr, moraw, NROW, 256, 512, 0);
        // postnorm: rmsnorm(mo_raw)*norm_w + u
        k_postnorm<<<NROW, 256, 0, stream>>>(moraw, norm_w, u, mo_of[p]);
    }

    // 7. wbuf = silu(xn @ W_wp^T + b_wp)     (K=128,N=256)
    k_gemm_mfma<1><<<dim3(4, 64), 256, 0, stream>>>(xn, W_wp, b_wp, nullptr, wbuf, NROW, 256, 128, 0);
    // 8. comb = wbuf * (mof + flip_c(mob))
    k_comb<<<NROW, 256, 0, stream>>>(wbuf, mof, mob, comb);
    // 9. out = comb @ W_out^T + b_out + x    (K=256,N=128)
    k_gemm_mfma<0><<<dim3(2, 64), 256, 0, stream>>>(comb, W_out, b_out, x, (float*)d_out, NROW, 128, 256, 0);
}

// Round 8
// 387.817 us; speedup vs baseline: 5.2938x; 1.1452x over previous
//
#include <hip/hip_runtime.h>
#include <math.h>

#define C_LEN 1024
#define NROW 4096   // B*C = 4*1024
#define NCHUNK 32
#define CHUNK 32    // C_LEN / NCHUNK

typedef __attribute__((ext_vector_type(8))) short short8;
typedef __attribute__((ext_vector_type(4))) float f32x4;

__device__ __forceinline__ float siluf(float x) { return x / (1.f + __expf(-x)); }

__device__ __forceinline__ unsigned short f2bf(float f) {
    unsigned u = __builtin_bit_cast(unsigned, f);
    unsigned r = (u + 0x7FFFu + ((u >> 16) & 1u)) >> 16;
    return (unsigned short)r;
}
__device__ __forceinline__ float bf2f(unsigned short v) {
    unsigned u = ((unsigned)v) << 16;
    return __builtin_bit_cast(float, u);
}

// ---------------- weight fp32 -> bf16 conversion (once per launch) ----------------
struct WTab {
    const float* s[11];
    unsigned short* d[11];
    int n[11];
};
__global__ __launch_bounds__(256) void k_w2bf(WTab t) {
    int seg = blockIdx.y;
    int n = t.n[seg];
    int i = (blockIdx.x * 256 + threadIdx.x) * 4;
    if (i < n) {
        float4 v = *(const float4*)(t.s[seg] + i);
        unsigned short* o = t.d[seg] + i;
        o[0] = f2bf(v.x); o[1] = f2bf(v.y); o[2] = f2bf(v.z); o[3] = f2bf(v.w);
    }
}

// ---------------- rmsnorm over rows of width 128 -> bf16 out ----------------
__global__ __launch_bounds__(256) void k_rmsnorm128(const float* __restrict__ x,
                                                    const float* __restrict__ w,
                                                    unsigned short* __restrict__ out) {
    int wave = threadIdx.x >> 6, lane = threadIdx.x & 63;
    int row = blockIdx.x * 4 + wave;
    float2 v = ((const float2*)(x + (size_t)row * 128))[lane];
    float ss = v.x * v.x + v.y * v.y;
    #pragma unroll
    for (int off = 32; off; off >>= 1) ss += __shfl_xor(ss, off, 64);
    float rs = rsqrtf(ss * (1.f / 128.f) + 1e-5f);
    float2 wv = ((const float2*)w)[lane];
    ushort2 o;
    o.x = f2bf(v.x * rs * wv.x);
    o.y = f2bf(v.y * rs * wv.y);
    ((ushort2*)(out + (size_t)row * 128))[lane] = o;
}

// ---------------- bf16-native MFMA GEMM ----------------
// C[M,N] = act(A[M,K](bf16) @ W[N,K](bf16)^T + bias) (+resid). Outputs fp32 (Cf)
// and/or bf16 (Cbf), either may be null. Tile 64x64, BK=64, 4 waves.
// flip!=0: logical row m reads physical A row with c -> C_LEN-1-c within batch.
// Requires M%64==0, K%64==0.
template<int ACT>
__global__ __launch_bounds__(256) void k_gemm_bf(const unsigned short* __restrict__ A,
                                                 const unsigned short* __restrict__ W,
                                                 const float* __restrict__ bias,
                                                 const float* __restrict__ resid,
                                                 float* __restrict__ Cf,
                                                 unsigned short* __restrict__ Cbf,
                                                 int M, int N, int K, int flip) {
    __shared__ __align__(16) unsigned short As[64 * 72];   // 72-pad: 2-way bank alias only
    __shared__ __align__(16) unsigned short Bs[64 * 72];
    int tid = threadIdx.x;
    int m0 = blockIdx.y * 64, n0 = blockIdx.x * 64;
    int w = tid >> 6, lane = tid & 63;
    int q = lane >> 4, ln = lane & 15;
    int srow = tid >> 2;            // 0..63 staging row
    int sseg = (tid & 3) * 16;      // 0,16,32,48 ushort offset in 64-k tile

    int mLog = m0 + srow;
    int mPhys = flip ? ((mLog & ~(C_LEN - 1)) | ((C_LEN - 1) - (mLog & (C_LEN - 1)))) : mLog;
    const unsigned short* pa = A + (size_t)mPhys * K + sseg;
    int nIdx = n0 + srow;
    const unsigned short* pw = W + (size_t)nIdx * K + sseg;
    bool nOK = (nIdx < N);

    f32x4 acc[4];
    #pragma unroll
    for (int j = 0; j < 4; ++j) acc[j] = (f32x4)(0.f);

    for (int k0 = 0; k0 < K; k0 += 64) {
        short8 a0 = *(const short8*)pa;
        short8 a1 = *(const short8*)(pa + 8);
        *(short8*)&As[srow * 72 + sseg] = a0;
        *(short8*)&As[srow * 72 + sseg + 8] = a1;
        short8 b0 = (short8)(0), b1 = (short8)(0);
        if (nOK) { b0 = *(const short8*)pw; b1 = *(const short8*)(pw + 8); }
        *(short8*)&Bs[srow * 72 + sseg] = b0;
        *(short8*)&Bs[srow * 72 + sseg + 8] = b1;
        pa += 64; pw += 64;
        __syncthreads();

        short8 af0 = *(const short8*)&As[(w * 16 + ln) * 72 + q * 8];
        short8 af1 = *(const short8*)&As[(w * 16 + ln) * 72 + 32 + q * 8];
        #pragma unroll
        for (int j = 0; j < 4; ++j) {
            short8 bf0 = *(const short8*)&Bs[(j * 16 + ln) * 72 + q * 8];
            short8 bf1 = *(const short8*)&Bs[(j * 16 + ln) * 72 + 32 + q * 8];
            acc[j] = __builtin_amdgcn_mfma_f32_16x16x32_bf16(af0, bf0, acc[j], 0, 0, 0);
            acc[j] = __builtin_amdgcn_mfma_f32_16x16x32_bf16(af1, bf1, acc[j], 0, 0, 0);
        }
        __syncthreads();
    }

    // epilogue: C/D layout col = lane&15, row = q*4 + reg
    #pragma unroll
    for (int j = 0; j < 4; ++j) {
        int nn = n0 + j * 16 + ln;
        if (nn < N) {
            float bsv = bias ? bias[nn] : 0.f;
            #pragma unroll
            for (int r = 0; r < 4; ++r) {
                int m = m0 + w * 16 + q * 4 + r;
                float v = acc[j][r] + bsv;
                if (ACT == 1) v = siluf(v);
                if (resid) v += resid[(size_t)m * N + nn];
                if (Cf)  Cf[(size_t)m * N + nn] = v;
                if (Cbf) Cbf[(size_t)m * N + nn] = f2bf(v);
            }
        }
    }
}

// ---------------- causal depthwise conv (K=4) + silu -> bf16 ----------------
__global__ __launch_bounds__(256) void k_conv(const float* __restrict__ xz,
                                              const float* __restrict__ cw,
                                              const float* __restrict__ cb,
                                              unsigned short* __restrict__ xconv_bf) {
    int d = blockIdx.x * 256 + threadIdx.x;   // 0..511
    int bc = blockIdx.y;                      // 0..4095
    int b = bc >> 10, c = bc & 1023;
    float acc = cb[d];
    const float* base = xz + (size_t)(b * C_LEN) * 1024 + d;
    #pragma unroll
    for (int k = 0; k < 4; ++k) {
        int cc = c - 3 + k;
        if (cc >= 0) acc = fmaf(cw[d * 4 + k], base[(size_t)cc * 1024], acc);
    }
    xconv_bf[(size_t)bc * 512 + d] = f2bf(siluf(acc));
}

// ---------------- dt projection: dt = softplus(dbl[:, :16] @ dt_w^T + dt_b) ----------------
__global__ __launch_bounds__(256) void k_dtproj(const float* __restrict__ dbl,
                                                const float* __restrict__ dtw,
                                                const float* __restrict__ dtb,
                                                float* __restrict__ dt) {
    int d = blockIdx.x * 256 + threadIdx.x;   // 0..511
    int r = blockIdx.y;                       // 0..4095
    float s = dtb[d];
    const float* row = dbl + (size_t)r * 48;
    #pragma unroll
    for (int j = 0; j < 16; ++j) s = fmaf(row[j], dtw[d * 16 + j], s);
    float sp = fmaxf(s, 0.f) + log1pf(__expf(-fabsf(s)));
    dt[(size_t)r * 512 + d] = sp;
}

// ---------------- chunked selective scan, pass 1 ----------------
// 8 n-states per lane, 2 lanes per d. block 256 = 128 d x 2 nh.
__global__ __launch_bounds__(256) void k_scan1(const float* __restrict__ dt,
                                               const unsigned short* __restrict__ xconv_bf,
                                               const float* __restrict__ dbl,
                                               const float* __restrict__ A_log,
                                               float* __restrict__ hfin,
                                               float* __restrict__ Pfin) {
    int tid = threadIdx.x;
    int nh = tid & 1, dl = tid >> 1;
    int k = blockIdx.x, dg = blockIdx.y, b = blockIdx.z;
    int d = dg * 128 + dl;
    float4 al0 = *(const float4*)&A_log[d * 16 + nh * 8];
    float4 al1 = *(const float4*)&A_log[d * 16 + nh * 8 + 4];
    float Ac[8] = {-__expf(al0.x), -__expf(al0.y), -__expf(al0.z), -__expf(al0.w),
                   -__expf(al1.x), -__expf(al1.y), -__expf(al1.z), -__expf(al1.w)};
    size_t r0 = (size_t)(b * C_LEN + k * CHUNK);
    const float* pdt = dt + r0 * 512 + d;
    const unsigned short* pxv = xconv_bf + r0 * 512 + d;
    const float* pB  = dbl + r0 * 48 + 16 + nh * 8;
    float h[8] = {0.f, 0.f, 0.f, 0.f, 0.f, 0.f, 0.f, 0.f};
    float sdt = 0.f;
    #pragma unroll 8
    for (int c = 0; c < CHUNK; ++c) {
        float dtv = *pdt;
        float xv  = bf2f(*pxv);
        float4 B0 = *(const float4*)pB;
        float4 B1 = *(const float4*)(pB + 4);
        float dx = dtv * xv;
        float Bv[8] = {B0.x, B0.y, B0.z, B0.w, B1.x, B1.y, B1.z, B1.w};
        #pragma unroll
        for (int j = 0; j < 8; ++j)
            h[j] = fmaf(__expf(dtv * Ac[j]), h[j], dx * Bv[j]);
        sdt += dtv;
        pdt += 512; pxv += 512; pB += 48;
    }
    size_t idx = ((size_t)(b * NCHUNK + k) * 512 + d) * 16 + nh * 8;
    *(float4*)&hfin[idx]     = make_float4(h[0], h[1], h[2], h[3]);
    *(float4*)&hfin[idx + 4] = make_float4(h[4], h[5], h[6], h[7]);
    *(float4*)&Pfin[idx]     = make_float4(__expf(Ac[0] * sdt), __expf(Ac[1] * sdt),
                                           __expf(Ac[2] * sdt), __expf(Ac[3] * sdt));
    *(float4*)&Pfin[idx + 4] = make_float4(__expf(Ac[4] * sdt), __expf(Ac[5] * sdt),
                                           __expf(Ac[6] * sdt), __expf(Ac[7] * sdt));
}

// ---------------- pass 2: sequential combine over chunks ----------------
__global__ __launch_bounds__(256) void k_scan2(const float* __restrict__ hfin,
                                               float* __restrict__ Pfin) {
    int t = blockIdx.x * 256 + threadIdx.x;   // (b*512+d)*16+n
    int b = t >> 13;
    int dn = t & 8191;
    float carry = 0.f;
    #pragma unroll
    for (int k = 0; k < NCHUNK; ++k) {
        size_t idx = (size_t)(b * NCHUNK + k) * 8192 + dn;
        float p = Pfin[idx];
        float hf = hfin[idx];
        Pfin[idx] = carry;
        carry = fmaf(p, carry, hf);
    }
}

// ---------------- pass 3: replay with carry-in; y + D skip + z gate -> bf16 ----------------
__global__ __launch_bounds__(256) void k_scan3(const float* __restrict__ dt,
                                               const unsigned short* __restrict__ xconv_bf,
                                               const float* __restrict__ dbl,
                                               const float* __restrict__ xz,
                                               const float* __restrict__ A_log,
                                               const float* __restrict__ Dp,
                                               const float* __restrict__ carryArr,
                                               unsigned short* __restrict__ gated_bf) {
    int tid = threadIdx.x;
    int nh = tid & 1, dl = tid >> 1;
    int k = blockIdx.x, dg = blockIdx.y, b = blockIdx.z;
    int d = dg * 128 + dl;
    float4 al0 = *(const float4*)&A_log[d * 16 + nh * 8];
    float4 al1 = *(const float4*)&A_log[d * 16 + nh * 8 + 4];
    float Ac[8] = {-__expf(al0.x), -__expf(al0.y), -__expf(al0.z), -__expf(al0.w),
                   -__expf(al1.x), -__expf(al1.y), -__expf(al1.z), -__expf(al1.w)};
    float Dd = Dp[d];
    size_t idx = ((size_t)(b * NCHUNK + k) * 512 + d) * 16 + nh * 8;
    float4 h0 = *(const float4*)&carryArr[idx];
    float4 h1 = *(const float4*)&carryArr[idx + 4];
    float h[8] = {h0.x, h0.y, h0.z, h0.w, h1.x, h1.y, h1.z, h1.w};
    size_t r0 = (size_t)(b * C_LEN + k * CHUNK);
    const float* pdt = dt + r0 * 512 + d;
    const unsigned short* pxv = xconv_bf + r0 * 512 + d;
    const float* pB  = dbl + r0 * 48 + 16 + nh * 8;
    const float* pC  = dbl + r0 * 48 + 32 + nh * 8;
    const float* pz  = xz + r0 * 1024 + 512 + d;
    unsigned short* pg = gated_bf + r0 * 512 + d;
    #pragma unroll 4
    for (int c = 0; c < CHUNK; ++c) {
        float dtv = *pdt;
        float xv  = bf2f(*pxv);
        float4 B0 = *(const float4*)pB;
        float4 B1 = *(const float4*)(pB + 4);
        float4 C0 = *(const float4*)pC;
        float4 C1 = *(const float4*)(pC + 4);
        float dx = dtv * xv;
        float Bv[8] = {B0.x, B0.y, B0.z, B0.w, B1.x, B1.y, B1.z, B1.w};
        float Cv[8] = {C0.x, C0.y, C0.z, C0.w, C1.x, C1.y, C1.z, C1.w};
        float contrib = 0.f;
        #pragma unroll
        for (int j = 0; j < 8; ++j) {
            h[j] = fmaf(__expf(dtv * Ac[j]), h[j], dx * Bv[j]);
            contrib = fmaf(h[j], Cv[j], contrib);
        }
        contrib += __shfl_xor(contrib, 1, 64);
        if (nh == 0) {
            float y = contrib + xv * Dd;
            float zv = *pz;
            *pg = f2bf(y * siluf(zv));
        }
        pdt += 512; pxv += 512; pB += 48; pC += 48; pz += 1024; pg += 512;
    }
}

// ---------------- postnorm: rmsnorm(mo, w) + u, width 256 ----------------
__global__ __launch_bounds__(256) void k_postnorm(const float* __restrict__ mo,
                                                  const float* __restrict__ w,
                                                  const float* __restrict__ u,
                                                  float* __restrict__ out) {
    __shared__ float red[4];
    int r = blockIdx.x, tid = threadIdx.x;
    float v = mo[(size_t)r * 256 + tid];
    float ss = v * v;
    #pragma unroll
    for (int off = 32; off; off >>= 1) ss += __shfl_xor(ss, off, 64);
    if ((tid & 63) == 0) red[tid >> 6] = ss;
    __syncthreads();
    float tot = red[0] + red[1] + red[2] + red[3];
    float rs = rsqrtf(tot * (1.f / 256.f) + 1e-5f);
    out[(size_t)r * 256 + tid] = v * rs * w[tid] + u[(size_t)r * 256 + tid];
}

// ---------------- combine: comb = silu_w * (mo_f + flip_c(mo_b)) -> bf16 ----------------
__global__ __launch_bounds__(256) void k_comb(const float* __restrict__ wbuf,
                                              const float* __restrict__ mof,
                                              const float* __restrict__ mob,
                                              unsigned short* __restrict__ comb_bf) {
    int r = blockIdx.x, tid = threadIdx.x;
    int b = r >> 10, c = r & 1023;
    int rb = (b << 10) | (1023 - c);
    float v = wbuf[(size_t)r * 256 + tid] *
              (mof[(size_t)r * 256 + tid] + mob[(size_t)rb * 256 + tid]);
    comb_bf[(size_t)r * 256 + tid] = f2bf(v);
}

extern "C" void kernel_launch(void* const* d_in, const int* in_sizes, int n_in,
                              void* d_out, int out_size, void* d_ws, size_t ws_size,
                              hipStream_t stream) {
    const float* x          = (const float*)d_in[0];
    const float* W_in       = (const float*)d_in[1];
    const float* b_in       = (const float*)d_in[2];
    const float* W_wp       = (const float*)d_in[3];
    const float* b_wp       = (const float*)d_in[4];
    const float* W_fp       = (const float*)d_in[5];
    const float* b_fp       = (const float*)d_in[6];
    const float* W_bp       = (const float*)d_in[7];
    const float* b_bp       = (const float*)d_in[8];
    const float* W_out      = (const float*)d_in[9];
    const float* b_out      = (const float*)d_in[10];
    const float* norm_w_top = (const float*)d_in[11];
    const float* mamba_p[2][10];
    for (int p = 0; p < 2; ++p)
        for (int i = 0; i < 10; ++i)
            mamba_p[p][i] = (const float*)d_in[12 + p * 10 + i];

    // ---- workspace layout (total 61,636,608 B; R5 proved >= 65.8 MB available) ----
    float* ws = (float*)d_ws;
    float* xz    = ws + 0;           // 4194304
    float* dbl   = ws + 4194304;     // 196608
    float* dtb   = ws + 4390912;     // 2097152
    float* uf    = ws + 6488064;     // 1048576
    float* ub    = ws + 7536640;     // 1048576
    float* mof   = ws + 8585216;     // 1048576
    float* mob   = ws + 9633792;     // 1048576  (float end: 10682368)
    float* moraw = xz;               // alias: xz dead when moraw written (after scan3)
    float* wbuf  = xz + 1048576;     // alias: xz dead at step 7
    float* Pfin  = mob;              // alias: mob written only by final postnorm

    unsigned short* us = (unsigned short*)(ws + 10682368);
    unsigned short* xn_bf    = us + 0;          // 524288
    unsigned short* ssm_bf   = us + 524288;     // 1048576
    unsigned short* uf_bf    = us + 1572864;    // 1048576
    unsigned short* ub_bf    = us + 2621440;    // 1048576
    unsigned short* xconv_bf = us + 3670016;    // 2097152
    unsigned short* gated_bf = us + 5767168;    // 2097152
    float* hfin = (float*)(us + 5767168);       // alias gated_bf: hfin dead before scan3 writes gated
    unsigned short* comb_bf  = ssm_bf;          // alias: ssm dead after step 4
    unsigned short* wb       = us + 7864320;    // weights region
    unsigned short* wb_W_in  = wb + 0;          // 32768
    unsigned short* wb_W_wp  = wb + 32768;      // 32768
    unsigned short* wb_W_fp  = wb + 65536;      // 65536
    unsigned short* wb_W_bp  = wb + 131072;     // 65536
    unsigned short* wb_W_out = wb + 196608;     // 32768
    unsigned short* wb_in[2]  = {wb + 229376, wb + 909312};   // 262144 each (in_w is 1024x256)
    unsigned short* wb_xp[2]  = {wb + 753664, wb + 1433600};  // 24576 each
    unsigned short* wb_outw[2]= {wb + 778240, wb + 1458176};  // 131072 each

    // 0. convert all weights to bf16 (single kernel, 11 segments)
    WTab t;
    t.s[0] = W_in;            t.d[0] = wb_W_in;   t.n[0] = 32768;
    t.s[1] = W_wp;            t.d[1] = wb_W_wp;   t.n[1] = 32768;
    t.s[2] = W_fp;            t.d[2] = wb_W_fp;   t.n[2] = 65536;
    t.s[3] = W_bp;            t.d[3] = wb_W_bp;   t.n[3] = 65536;
    t.s[4] = W_out;           t.d[4] = wb_W_out;  t.n[4] = 32768;
    t.s[5] = mamba_p[0][0];   t.d[5] = wb_in[0];  t.n[5] = 262144;   // FIX: in_w = 1024*256
    t.s[6] = mamba_p[0][3];   t.d[6] = wb_xp[0];  t.n[6] = 24576;
    t.s[7] = mamba_p[0][8];   t.d[7] = wb_outw[0];t.n[7] = 131072;
    t.s[8] = mamba_p[1][0];   t.d[8] = wb_in[1];  t.n[8] = 262144;   // FIX: in_w = 1024*256
    t.s[9] = mamba_p[1][3];   t.d[9] = wb_xp[1];  t.n[9] = 24576;
    t.s[10]= mamba_p[1][8];   t.d[10]= wb_outw[1];t.n[10]= 131072;
    k_w2bf<<<dim3(512, 11), 256, 0, stream>>>(t);

    // 1. top rmsnorm -> bf16
    k_rmsnorm128<<<NROW / 4, 256, 0, stream>>>(x, norm_w_top, xn_bf);
    // 2. ssm = xn @ W_in^T + b_in           (K=128,N=256) -> bf16 only
    k_gemm_bf<0><<<dim3(4, 64), 256, 0, stream>>>(xn_bf, wb_W_in, b_in, nullptr,
                                                  nullptr, ssm_bf, NROW, 256, 128, 0);
    // 3. u_f = ssm @ W_fp^T + b_fp          (K=256,N=256) -> fp32 + bf16
    k_gemm_bf<0><<<dim3(4, 64), 256, 0, stream>>>(ssm_bf, wb_W_fp, b_fp, nullptr,
                                                  uf, uf_bf, NROW, 256, 256, 0);
    // 4. u_b = flip_c(ssm) @ W_bp^T + b_bp  -> fp32 + bf16
    k_gemm_bf<0><<<dim3(4, 64), 256, 0, stream>>>(ssm_bf, wb_W_bp, b_bp, nullptr,
                                                  ub, ub_bf, NROW, 256, 256, 1);

    const unsigned short* ubf_of[2] = {uf_bf, ub_bf};
    const float* u_of[2] = {uf, ub};
    float* mo_of[2] = {mof, mob};
    for (int p = 0; p < 2; ++p) {
        const float* conv_w = mamba_p[p][1];
        const float* conv_b = mamba_p[p][2];
        const float* dt_w   = mamba_p[p][4];
        const float* dt_b   = mamba_p[p][5];
        const float* A_log  = mamba_p[p][6];
        const float* Dp     = mamba_p[p][7];
        const float* norm_w = mamba_p[p][9];

        // xz = u @ in_w^T                    (K=256,N=1024) -> fp32
        k_gemm_bf<0><<<dim3(16, 64), 256, 0, stream>>>(ubf_of[p], wb_in[p], nullptr, nullptr,
                                                       xz, nullptr, NROW, 1024, 256, 0);
        // causal depthwise conv + silu -> bf16
        k_conv<<<dim3(2, NROW), 256, 0, stream>>>(xz, conv_w, conv_b, xconv_bf);
        // dbl = xconv @ xproj_w^T            (K=512,N=48) -> fp32
        k_gemm_bf<0><<<dim3(1, 64), 256, 0, stream>>>(xconv_bf, wb_xp[p], nullptr, nullptr,
                                                      dbl, nullptr, NROW, 48, 512, 0);
        // dt = softplus(dbl[:, :16] @ dt_w^T + dt_b)
        k_dtproj<<<dim3(2, NROW), 256, 0, stream>>>(dbl, dt_w, dt_b, dtb);
        // chunked selective scan (3 passes); scan3 emits bf16 gated
        k_scan1<<<dim3(NCHUNK, 4, 4), 256, 0, stream>>>(dtb, xconv_bf, dbl, A_log, hfin, Pfin);
        k_scan2<<<128, 256, 0, stream>>>(hfin, Pfin);
        k_scan3<<<dim3(NCHUNK, 4, 4), 256, 0, stream>>>(dtb, xconv_bf, dbl, xz, A_log, Dp,
                                                        Pfin, gated_bf);
        // mo_raw = gated @ out_w^T           (K=512,N=256) -> fp32 (moraw aliases xz)
        k_gemm_bf<0><<<dim3(4, 64), 256, 0, stream>>>(gated_bf, wb_outw[p], nullptr, nullptr,
                                                      moraw, nullptr, NROW, 256, 512, 0);
        // postnorm: rmsnorm(mo_raw)*norm_w + u
        k_postnorm<<<NROW, 256, 0, stream>>>(moraw, norm_w, u_of[p], mo_of[p]);
    }

    // 7. wbuf = silu(xn @ W_wp^T + b_wp)     (K=128,N=256) -> fp32
    k_gemm_bf<1><<<dim3(4, 64), 256, 0, stream>>>(xn_bf, wb_W_wp, b_wp, nullptr,
                                                  wbuf, nullptr, NROW, 256, 128, 0);
    // 8. comb = wbuf * (mof + flip_c(mob)) -> bf16
    k_comb<<<NROW, 256, 0, stream>>>(wbuf, mof, mob, comb_bf);
    // 9. out = comb @ W_out^T + b_out + x    (K=256,N=128) -> fp32
    k_gemm_bf<0><<<dim3(2, 64), 256, 0, stream>>>(comb_bf, wb_W_out, b_out, x,
                                                  (float*)d_out, nullptr, NROW, 128, 256, 0);
}

// Round 9
// 356.484 us; speedup vs baseline: 5.7590x; 1.0879x over previous
//
#include <hip/hip_runtime.h>
#include <math.h>

#define C_LEN 1024
#define NROW 4096   // B*C = 4*1024
#define NCHUNK 32
#define CHUNK 32    // C_LEN / NCHUNK

typedef __attribute__((ext_vector_type(8))) short short8;
typedef __attribute__((ext_vector_type(4))) float f32x4;

__device__ __forceinline__ float siluf(float x) { return x / (1.f + __expf(-x)); }

__device__ __forceinline__ unsigned short f2bf(float f) {
    unsigned u = __builtin_bit_cast(unsigned, f);
    unsigned r = (u + 0x7FFFu + ((u >> 16) & 1u)) >> 16;
    return (unsigned short)r;
}
__device__ __forceinline__ float bf2f(unsigned short v) {
    unsigned u = ((unsigned)v) << 16;
    return __builtin_bit_cast(float, u);
}

// ---------------- weight fp32 -> bf16 conversion (once per launch) ----------------
struct WTab {
    const float* s[11];
    unsigned short* d[11];
    int n[11];
};
__global__ __launch_bounds__(256) void k_w2bf(WTab t) {
    int seg = blockIdx.y;
    int n = t.n[seg];
    int i = (blockIdx.x * 256 + threadIdx.x) * 4;
    if (i < n) {
        float4 v = *(const float4*)(t.s[seg] + i);
        unsigned short* o = t.d[seg] + i;
        o[0] = f2bf(v.x); o[1] = f2bf(v.y); o[2] = f2bf(v.z); o[3] = f2bf(v.w);
    }
}

// ---------------- rmsnorm over rows of width 128 -> bf16 out ----------------
__global__ __launch_bounds__(256) void k_rmsnorm128(const float* __restrict__ x,
                                                    const float* __restrict__ w,
                                                    unsigned short* __restrict__ out) {
    int wave = threadIdx.x >> 6, lane = threadIdx.x & 63;
    int row = blockIdx.x * 4 + wave;
    float2 v = ((const float2*)(x + (size_t)row * 128))[lane];
    float ss = v.x * v.x + v.y * v.y;
    #pragma unroll
    for (int off = 32; off; off >>= 1) ss += __shfl_xor(ss, off, 64);
    float rs = rsqrtf(ss * (1.f / 128.f) + 1e-5f);
    float2 wv = ((const float2*)w)[lane];
    ushort2 o;
    o.x = f2bf(v.x * rs * wv.x);
    o.y = f2bf(v.y * rs * wv.y);
    ((ushort2*)(out + (size_t)row * 128))[lane] = o;
}

// ---------------- bf16-native MFMA GEMM ----------------
// C[M,N] = act(A[M,K](bf16) @ W[N,K](bf16)^T + bias) (+resid). Outputs fp32 (Cf)
// and/or bf16 (Cbf); either may be null. Tile 64x64, BK=64, 4 waves.
template<int ACT>
__global__ __launch_bounds__(256) void k_gemm_bf(const unsigned short* __restrict__ A,
                                                 const unsigned short* __restrict__ W,
                                                 const float* __restrict__ bias,
                                                 const float* __restrict__ resid,
                                                 float* __restrict__ Cf,
                                                 unsigned short* __restrict__ Cbf,
                                                 int M, int N, int K, int flip) {
    __shared__ __align__(16) unsigned short As[64 * 72];
    __shared__ __align__(16) unsigned short Bs[64 * 72];
    int tid = threadIdx.x;
    int m0 = blockIdx.y * 64, n0 = blockIdx.x * 64;
    int w = tid >> 6, lane = tid & 63;
    int q = lane >> 4, ln = lane & 15;
    int srow = tid >> 2;
    int sseg = (tid & 3) * 16;

    int mLog = m0 + srow;
    int mPhys = flip ? (mLog ^ (C_LEN - 1)) : mLog;
    const unsigned short* pa = A + (size_t)mPhys * K + sseg;
    int nIdx = n0 + srow;
    const unsigned short* pw = W + (size_t)nIdx * K + sseg;
    bool nOK = (nIdx < N);

    f32x4 acc[4];
    #pragma unroll
    for (int j = 0; j < 4; ++j) acc[j] = (f32x4)(0.f);

    for (int k0 = 0; k0 < K; k0 += 64) {
        short8 a0 = *(const short8*)pa;
        short8 a1 = *(const short8*)(pa + 8);
        *(short8*)&As[srow * 72 + sseg] = a0;
        *(short8*)&As[srow * 72 + sseg + 8] = a1;
        short8 b0 = (short8)(0), b1 = (short8)(0);
        if (nOK) { b0 = *(const short8*)pw; b1 = *(const short8*)(pw + 8); }
        *(short8*)&Bs[srow * 72 + sseg] = b0;
        *(short8*)&Bs[srow * 72 + sseg + 8] = b1;
        pa += 64; pw += 64;
        __syncthreads();

        short8 af0 = *(const short8*)&As[(w * 16 + ln) * 72 + q * 8];
        short8 af1 = *(const short8*)&As[(w * 16 + ln) * 72 + 32 + q * 8];
        #pragma unroll
        for (int j = 0; j < 4; ++j) {
            short8 bf0 = *(const short8*)&Bs[(j * 16 + ln) * 72 + q * 8];
            short8 bf1 = *(const short8*)&Bs[(j * 16 + ln) * 72 + 32 + q * 8];
            acc[j] = __builtin_amdgcn_mfma_f32_16x16x32_bf16(af0, bf0, acc[j], 0, 0, 0);
            acc[j] = __builtin_amdgcn_mfma_f32_16x16x32_bf16(af1, bf1, acc[j], 0, 0, 0);
        }
        __syncthreads();
    }

    #pragma unroll
    for (int j = 0; j < 4; ++j) {
        int nn = n0 + j * 16 + ln;
        if (nn < N) {
            float bsv = bias ? bias[nn] : 0.f;
            #pragma unroll
            for (int r = 0; r < 4; ++r) {
                int m = m0 + w * 16 + q * 4 + r;
                float v = acc[j][r] + bsv;
                if (ACT == 1) v = siluf(v);
                if (resid) v += resid[(size_t)m * N + nn];
                if (Cf)  Cf[(size_t)m * N + nn] = v;
                if (Cbf) Cbf[(size_t)m * N + nn] = f2bf(v);
            }
        }
    }
}

// ---------------- final GEMM with comb fused into A-staging ----------------
// A[m, c] = wbuf[m,c] * (mof[m,c] + mob[m^1023, c]), all bf16, Kc = 256.
// out = A @ W_out^T + b_out + x (fp32).
__global__ __launch_bounds__(256) void k_gemm_comb(const unsigned short* __restrict__ wbuf,
                                                   const unsigned short* __restrict__ mof,
                                                   const unsigned short* __restrict__ mob,
                                                   const unsigned short* __restrict__ W,
                                                   const float* __restrict__ bias,
                                                   const float* __restrict__ resid,
                                                   float* __restrict__ Cf,
                                                   int N, int K) {
    __shared__ __align__(16) unsigned short As[64 * 72];
    __shared__ __align__(16) unsigned short Bs[64 * 72];
    int tid = threadIdx.x;
    int m0 = blockIdx.y * 64, n0 = blockIdx.x * 64;
    int w = tid >> 6, lane = tid & 63;
    int q = lane >> 4, ln = lane & 15;
    int srow = tid >> 2;
    int sseg = (tid & 3) * 16;

    int mLog = m0 + srow;
    int mFlip = mLog ^ (C_LEN - 1);
    int nIdx = n0 + srow;
    const unsigned short* pw = W + (size_t)nIdx * K + sseg;
    bool nOK = (nIdx < N);

    f32x4 acc[4];
    #pragma unroll
    for (int j = 0; j < 4; ++j) acc[j] = (f32x4)(0.f);

    for (int k0 = 0; k0 < K; k0 += 64) {
        size_t off  = (size_t)mLog * 256 + k0 + sseg;
        size_t offb = (size_t)mFlip * 256 + k0 + sseg;
        #pragma unroll
        for (int h = 0; h < 2; ++h) {
            short8 aw = *(const short8*)(wbuf + off + h * 8);
            short8 af = *(const short8*)(mof + off + h * 8);
            short8 ab = *(const short8*)(mob + offb + h * 8);
            short8 av;
            #pragma unroll
            for (int j = 0; j < 8; ++j)
                av[j] = (short)f2bf(bf2f((unsigned short)aw[j]) *
                                    (bf2f((unsigned short)af[j]) + bf2f((unsigned short)ab[j])));
            *(short8*)&As[srow * 72 + sseg + h * 8] = av;
        }
        short8 b0 = (short8)(0), b1 = (short8)(0);
        if (nOK) { b0 = *(const short8*)pw; b1 = *(const short8*)(pw + 8); }
        *(short8*)&Bs[srow * 72 + sseg] = b0;
        *(short8*)&Bs[srow * 72 + sseg + 8] = b1;
        pw += 64;
        __syncthreads();

        short8 af0 = *(const short8*)&As[(w * 16 + ln) * 72 + q * 8];
        short8 af1 = *(const short8*)&As[(w * 16 + ln) * 72 + 32 + q * 8];
        #pragma unroll
        for (int j = 0; j < 4; ++j) {
            short8 bf0 = *(const short8*)&Bs[(j * 16 + ln) * 72 + q * 8];
            short8 bf1 = *(const short8*)&Bs[(j * 16 + ln) * 72 + 32 + q * 8];
            acc[j] = __builtin_amdgcn_mfma_f32_16x16x32_bf16(af0, bf0, acc[j], 0, 0, 0);
            acc[j] = __builtin_amdgcn_mfma_f32_16x16x32_bf16(af1, bf1, acc[j], 0, 0, 0);
        }
        __syncthreads();
    }

    #pragma unroll
    for (int j = 0; j < 4; ++j) {
        int nn = n0 + j * 16 + ln;
        if (nn < N) {
            float bsv = bias[nn];
            #pragma unroll
            for (int r = 0; r < 4; ++r) {
                int m = m0 + w * 16 + q * 4 + r;
                Cf[(size_t)m * N + nn] = acc[j][r] + bsv + resid[(size_t)m * N + nn];
            }
        }
    }
}

// ---------------- causal depthwise conv (K=4) + silu: bf16 in/out ----------------
// 16 c-positions per thread with register sliding window.
__global__ __launch_bounds__(256) void k_conv(const unsigned short* __restrict__ xz,
                                              const float* __restrict__ cw,
                                              const float* __restrict__ cb,
                                              unsigned short* __restrict__ xconv_bf) {
    int d = blockIdx.x * 256 + threadIdx.x;   // 0..511
    int by = blockIdx.y;                      // 0..255
    int b = by >> 6, c0 = (by & 63) * 16;
    float4 cwv = *(const float4*)(cw + d * 4);
    float bias = cb[d];
    const unsigned short* base = xz + (size_t)(b * C_LEN) * 1024 + d;
    float w0 = 0.f, w1 = 0.f, w2 = 0.f;
    if (c0) {
        w0 = bf2f(base[(size_t)(c0 - 3) * 1024]);
        w1 = bf2f(base[(size_t)(c0 - 2) * 1024]);
        w2 = bf2f(base[(size_t)(c0 - 1) * 1024]);
    }
    unsigned short* out = xconv_bf + (size_t)(b * C_LEN + c0) * 512 + d;
    #pragma unroll
    for (int i = 0; i < 16; ++i) {
        float cur = bf2f(base[(size_t)(c0 + i) * 1024]);
        float acc = bias;
        acc = fmaf(cwv.x, w0, acc);
        acc = fmaf(cwv.y, w1, acc);
        acc = fmaf(cwv.z, w2, acc);
        acc = fmaf(cwv.w, cur, acc);
        out[(size_t)i * 512] = f2bf(siluf(acc));
        w0 = w1; w1 = w2; w2 = cur;
    }
}

// ---------------- dt projection, 8 rows per thread ----------------
__global__ __launch_bounds__(256) void k_dtproj(const float* __restrict__ dbl,
                                                const float* __restrict__ dtw,
                                                const float* __restrict__ dtb,
                                                float* __restrict__ dt) {
    int d = blockIdx.x * 256 + threadIdx.x;   // 0..511
    int r0 = blockIdx.y * 8;                  // 0..4088
    float4 w0 = *(const float4*)(dtw + d * 16);
    float4 w1 = *(const float4*)(dtw + d * 16 + 4);
    float4 w2 = *(const float4*)(dtw + d * 16 + 8);
    float4 w3 = *(const float4*)(dtw + d * 16 + 12);
    float bias = dtb[d];
    #pragma unroll
    for (int rr = 0; rr < 8; ++rr) {
        int r = r0 + rr;
        const float* row = dbl + (size_t)r * 48;
        float s = bias;
        s = fmaf(row[0], w0.x, s);  s = fmaf(row[1], w0.y, s);
        s = fmaf(row[2], w0.z, s);  s = fmaf(row[3], w0.w, s);
        s = fmaf(row[4], w1.x, s);  s = fmaf(row[5], w1.y, s);
        s = fmaf(row[6], w1.z, s);  s = fmaf(row[7], w1.w, s);
        s = fmaf(row[8], w2.x, s);  s = fmaf(row[9], w2.y, s);
        s = fmaf(row[10], w2.z, s); s = fmaf(row[11], w2.w, s);
        s = fmaf(row[12], w3.x, s); s = fmaf(row[13], w3.y, s);
        s = fmaf(row[14], w3.z, s); s = fmaf(row[15], w3.w, s);
        float sp = fmaxf(s, 0.f) + log1pf(__expf(-fabsf(s)));
        dt[(size_t)r * 512 + d] = sp;
    }
}

// ---------------- chunked selective scan, pass 1 ----------------
__global__ __launch_bounds__(256) void k_scan1(const float* __restrict__ dt,
                                               const unsigned short* __restrict__ xconv_bf,
                                               const float* __restrict__ dbl,
                                               const float* __restrict__ A_log,
                                               float* __restrict__ hfin,
                                               float* __restrict__ Pfin) {
    int tid = threadIdx.x;
    int nh = tid & 1, dl = tid >> 1;
    int k = blockIdx.x, dg = blockIdx.y, b = blockIdx.z;
    int d = dg * 128 + dl;
    float4 al0 = *(const float4*)&A_log[d * 16 + nh * 8];
    float4 al1 = *(const float4*)&A_log[d * 16 + nh * 8 + 4];
    float Ac[8] = {-__expf(al0.x), -__expf(al0.y), -__expf(al0.z), -__expf(al0.w),
                   -__expf(al1.x), -__expf(al1.y), -__expf(al1.z), -__expf(al1.w)};
    size_t r0 = (size_t)(b * C_LEN + k * CHUNK);
    const float* pdt = dt + r0 * 512 + d;
    const unsigned short* pxv = xconv_bf + r0 * 512 + d;
    const float* pB  = dbl + r0 * 48 + 16 + nh * 8;
    float h[8] = {0.f, 0.f, 0.f, 0.f, 0.f, 0.f, 0.f, 0.f};
    float sdt = 0.f;
    #pragma unroll 8
    for (int c = 0; c < CHUNK; ++c) {
        float dtv = *pdt;
        float xv  = bf2f(*pxv);
        float4 B0 = *(const float4*)pB;
        float4 B1 = *(const float4*)(pB + 4);
        float dx = dtv * xv;
        float Bv[8] = {B0.x, B0.y, B0.z, B0.w, B1.x, B1.y, B1.z, B1.w};
        #pragma unroll
        for (int j = 0; j < 8; ++j)
            h[j] = fmaf(__expf(dtv * Ac[j]), h[j], dx * Bv[j]);
        sdt += dtv;
        pdt += 512; pxv += 512; pB += 48;
    }
    size_t idx = ((size_t)(b * NCHUNK + k) * 512 + d) * 16 + nh * 8;
    *(float4*)&hfin[idx]     = make_float4(h[0], h[1], h[2], h[3]);
    *(float4*)&hfin[idx + 4] = make_float4(h[4], h[5], h[6], h[7]);
    *(float4*)&Pfin[idx]     = make_float4(__expf(Ac[0] * sdt), __expf(Ac[1] * sdt),
                                           __expf(Ac[2] * sdt), __expf(Ac[3] * sdt));
    *(float4*)&Pfin[idx + 4] = make_float4(__expf(Ac[4] * sdt), __expf(Ac[5] * sdt),
                                           __expf(Ac[6] * sdt), __expf(Ac[7] * sdt));
}

// ---------------- pass 2: sequential combine over chunks ----------------
__global__ __launch_bounds__(256) void k_scan2(const float* __restrict__ hfin,
                                               float* __restrict__ Pfin) {
    int t = blockIdx.x * 256 + threadIdx.x;
    int b = t >> 13;
    int dn = t & 8191;
    float carry = 0.f;
    #pragma unroll
    for (int k = 0; k < NCHUNK; ++k) {
        size_t idx = (size_t)(b * NCHUNK + k) * 8192 + dn;
        float p = Pfin[idx];
        float hf = hfin[idx];
        Pfin[idx] = carry;
        carry = fmaf(p, carry, hf);
    }
}

// ---------------- pass 3: replay with carry-in; y + D skip + z gate -> bf16 ----------------
__global__ __launch_bounds__(256) void k_scan3(const float* __restrict__ dt,
                                               const unsigned short* __restrict__ xconv_bf,
                                               const float* __restrict__ dbl,
                                               const unsigned short* __restrict__ xz,
                                               const float* __restrict__ A_log,
                                               const float* __restrict__ Dp,
                                               const float* __restrict__ carryArr,
                                               unsigned short* __restrict__ gated_bf) {
    int tid = threadIdx.x;
    int nh = tid & 1, dl = tid >> 1;
    int k = blockIdx.x, dg = blockIdx.y, b = blockIdx.z;
    int d = dg * 128 + dl;
    float4 al0 = *(const float4*)&A_log[d * 16 + nh * 8];
    float4 al1 = *(const float4*)&A_log[d * 16 + nh * 8 + 4];
    float Ac[8] = {-__expf(al0.x), -__expf(al0.y), -__expf(al0.z), -__expf(al0.w),
                   -__expf(al1.x), -__expf(al1.y), -__expf(al1.z), -__expf(al1.w)};
    float Dd = Dp[d];
    size_t idx = ((size_t)(b * NCHUNK + k) * 512 + d) * 16 + nh * 8;
    float4 h0 = *(const float4*)&carryArr[idx];
    float4 h1 = *(const float4*)&carryArr[idx + 4];
    float h[8] = {h0.x, h0.y, h0.z, h0.w, h1.x, h1.y, h1.z, h1.w};
    size_t r0 = (size_t)(b * C_LEN + k * CHUNK);
    const float* pdt = dt + r0 * 512 + d;
    const unsigned short* pxv = xconv_bf + r0 * 512 + d;
    const float* pB  = dbl + r0 * 48 + 16 + nh * 8;
    const float* pC  = dbl + r0 * 48 + 32 + nh * 8;
    const unsigned short* pz = xz + r0 * 1024 + 512 + d;
    unsigned short* pg = gated_bf + r0 * 512 + d;
    #pragma unroll 4
    for (int c = 0; c < CHUNK; ++c) {
        float dtv = *pdt;
        float xv  = bf2f(*pxv);
        float4 B0 = *(const float4*)pB;
        float4 B1 = *(const float4*)(pB + 4);
        float4 C0 = *(const float4*)pC;
        float4 C1 = *(const float4*)(pC + 4);
        float dx = dtv * xv;
        float Bv[8] = {B0.x, B0.y, B0.z, B0.w, B1.x, B1.y, B1.z, B1.w};
        float Cv[8] = {C0.x, C0.y, C0.z, C0.w, C1.x, C1.y, C1.z, C1.w};
        float contrib = 0.f;
        #pragma unroll
        for (int j = 0; j < 8; ++j) {
            h[j] = fmaf(__expf(dtv * Ac[j]), h[j], dx * Bv[j]);
            contrib = fmaf(h[j], Cv[j], contrib);
        }
        contrib += __shfl_xor(contrib, 1, 64);
        if (nh == 0) {
            float y = contrib + xv * Dd;
            float zv = bf2f(*pz);
            *pg = f2bf(y * siluf(zv));
        }
        pdt += 512; pxv += 512; pB += 48; pC += 48; pz += 1024; pg += 512;
    }
}

// ---------------- postnorm: rmsnorm(mo_bf)*w + u_bf -> bf16, width 256 ----------------
__global__ __launch_bounds__(256) void k_postnorm(const unsigned short* __restrict__ mo,
                                                  const float* __restrict__ w,
                                                  const unsigned short* __restrict__ u,
                                                  unsigned short* __restrict__ out) {
    __shared__ float red[4];
    int r = blockIdx.x, tid = threadIdx.x;
    float v = bf2f(mo[(size_t)r * 256 + tid]);
    float ss = v * v;
    #pragma unroll
    for (int off = 32; off; off >>= 1) ss += __shfl_xor(ss, off, 64);
    if ((tid & 63) == 0) red[tid >> 6] = ss;
    __syncthreads();
    float tot = red[0] + red[1] + red[2] + red[3];
    float rs = rsqrtf(tot * (1.f / 256.f) + 1e-5f);
    out[(size_t)r * 256 + tid] = f2bf(v * rs * w[tid] + bf2f(u[(size_t)r * 256 + tid]));
}

extern "C" void kernel_launch(void* const* d_in, const int* in_sizes, int n_in,
                              void* d_out, int out_size, void* d_ws, size_t ws_size,
                              hipStream_t stream) {
    const float* x          = (const float*)d_in[0];
    const float* W_in       = (const float*)d_in[1];
    const float* b_in       = (const float*)d_in[2];
    const float* W_wp       = (const float*)d_in[3];
    const float* b_wp       = (const float*)d_in[4];
    const float* W_fp       = (const float*)d_in[5];
    const float* b_fp       = (const float*)d_in[6];
    const float* W_bp       = (const float*)d_in[7];
    const float* b_bp       = (const float*)d_in[8];
    const float* W_out      = (const float*)d_in[9];
    const float* b_out      = (const float*)d_in[10];
    const float* norm_w_top = (const float*)d_in[11];
    const float* mamba_p[2][10];
    for (int p = 0; p < 2; ++p)
        for (int i = 0; i < 10; ++i)
            mamba_p[p][i] = (const float*)d_in[12 + p * 10 + i];

    // ---- workspace: fp32 region then bf16 region; total 52.2 MB, NO aliasing ----
    float* ws = (float*)d_ws;
    float* dbl  = ws + 0;         // 196608
    float* dtb  = ws + 196608;    // 2097152
    float* hfin = ws + 2293760;   // 1048576
    float* Pfin = ws + 3342336;   // 1048576 (fp32 end: 4390912)

    unsigned short* us = (unsigned short*)(ws + 4390912);
    unsigned short* xn_bf    = us + 0;          // 524288
    unsigned short* ssm_bf   = us + 524288;     // 1048576
    unsigned short* uf_bf    = us + 1572864;    // 1048576
    unsigned short* ub_bf    = us + 2621440;    // 1048576
    unsigned short* xz_bf    = us + 3670016;    // 4194304
    unsigned short* xconv_bf = us + 7864320;    // 2097152
    unsigned short* gated_bf = us + 9961472;    // 2097152
    unsigned short* moraw_bf = us + 12058624;   // 1048576
    unsigned short* mof_bf   = us + 13107200;   // 1048576
    unsigned short* mob_bf   = us + 14155776;   // 1048576
    unsigned short* wbuf_bf  = us + 15204352;   // 1048576
    unsigned short* wb       = us + 16252928;   // weights (1064960)
    unsigned short* wb_W_in  = wb + 0;          // 32768
    unsigned short* wb_W_wp  = wb + 32768;      // 32768
    unsigned short* wb_W_fp  = wb + 65536;      // 65536
    unsigned short* wb_W_bp  = wb + 131072;     // 65536
    unsigned short* wb_W_out = wb + 196608;     // 32768
    unsigned short* wb_in[2]  = {wb + 229376, wb + 647168};   // 262144 each
    unsigned short* wb_xp[2]  = {wb + 491520, wb + 909312};   // 24576 each
    unsigned short* wb_outw[2]= {wb + 516096, wb + 933888};   // 131072 each

    // 0. convert all weights to bf16
    WTab t;
    t.s[0] = W_in;            t.d[0] = wb_W_in;   t.n[0] = 32768;
    t.s[1] = W_wp;            t.d[1] = wb_W_wp;   t.n[1] = 32768;
    t.s[2] = W_fp;            t.d[2] = wb_W_fp;   t.n[2] = 65536;
    t.s[3] = W_bp;            t.d[3] = wb_W_bp;   t.n[3] = 65536;
    t.s[4] = W_out;           t.d[4] = wb_W_out;  t.n[4] = 32768;
    t.s[5] = mamba_p[0][0];   t.d[5] = wb_in[0];  t.n[5] = 262144;
    t.s[6] = mamba_p[0][3];   t.d[6] = wb_xp[0];  t.n[6] = 24576;
    t.s[7] = mamba_p[0][8];   t.d[7] = wb_outw[0];t.n[7] = 131072;
    t.s[8] = mamba_p[1][0];   t.d[8] = wb_in[1];  t.n[8] = 262144;
    t.s[9] = mamba_p[1][3];   t.d[9] = wb_xp[1];  t.n[9] = 24576;
    t.s[10]= mamba_p[1][8];   t.d[10]= wb_outw[1];t.n[10]= 131072;
    k_w2bf<<<dim3(256, 11), 256, 0, stream>>>(t);

    // 1. top rmsnorm -> bf16
    k_rmsnorm128<<<NROW / 4, 256, 0, stream>>>(x, norm_w_top, xn_bf);
    // 2. ssm = xn @ W_in^T + b_in           (K=128,N=256) -> bf16
    k_gemm_bf<0><<<dim3(4, 64), 256, 0, stream>>>(xn_bf, wb_W_in, b_in, nullptr,
                                                  nullptr, ssm_bf, NROW, 256, 128, 0);
    // 3. u_f = ssm @ W_fp^T + b_fp          (K=256,N=256) -> bf16
    k_gemm_bf<0><<<dim3(4, 64), 256, 0, stream>>>(ssm_bf, wb_W_fp, b_fp, nullptr,
                                                  nullptr, uf_bf, NROW, 256, 256, 0);
    // 4. u_b = flip_c(ssm) @ W_bp^T + b_bp  -> bf16
    k_gemm_bf<0><<<dim3(4, 64), 256, 0, stream>>>(ssm_bf, wb_W_bp, b_bp, nullptr,
                                                  nullptr, ub_bf, NROW, 256, 256, 1);

    const unsigned short* ubf_of[2] = {uf_bf, ub_bf};
    unsigned short* mo_of[2] = {mof_bf, mob_bf};
    for (int p = 0; p < 2; ++p) {
        const float* conv_w = mamba_p[p][1];
        const float* conv_b = mamba_p[p][2];
        const float* dt_w   = mamba_p[p][4];
        const float* dt_b   = mamba_p[p][5];
        const float* A_log  = mamba_p[p][6];
        const float* Dp     = mamba_p[p][7];
        const float* norm_w = mamba_p[p][9];

        // xz = u @ in_w^T                    (K=256,N=1024) -> bf16
        k_gemm_bf<0><<<dim3(16, 64), 256, 0, stream>>>(ubf_of[p], wb_in[p], nullptr, nullptr,
                                                       nullptr, xz_bf, NROW, 1024, 256, 0);
        // causal depthwise conv + silu -> bf16
        k_conv<<<dim3(2, 256), 256, 0, stream>>>(xz_bf, conv_w, conv_b, xconv_bf);
        // dbl = xconv @ xproj_w^T            (K=512,N=48) -> fp32
        k_gemm_bf<0><<<dim3(1, 64), 256, 0, stream>>>(xconv_bf, wb_xp[p], nullptr, nullptr,
                                                      dbl, nullptr, NROW, 48, 512, 0);
        // dt = softplus(dbl[:, :16] @ dt_w^T + dt_b)
        k_dtproj<<<dim3(2, 512), 256, 0, stream>>>(dbl, dt_w, dt_b, dtb);
        // chunked selective scan (3 passes)
        k_scan1<<<dim3(NCHUNK, 4, 4), 256, 0, stream>>>(dtb, xconv_bf, dbl, A_log, hfin, Pfin);
        k_scan2<<<128, 256, 0, stream>>>(hfin, Pfin);
        k_scan3<<<dim3(NCHUNK, 4, 4), 256, 0, stream>>>(dtb, xconv_bf, dbl, xz_bf, A_log, Dp,
                                                        Pfin, gated_bf);
        // mo_raw = gated @ out_w^T           (K=512,N=256) -> bf16
        k_gemm_bf<0><<<dim3(4, 64), 256, 0, stream>>>(gated_bf, wb_outw[p], nullptr, nullptr,
                                                      nullptr, moraw_bf, NROW, 256, 512, 0);
        // postnorm: rmsnorm(mo_raw)*norm_w + u -> bf16
        k_postnorm<<<NROW, 256, 0, stream>>>(moraw_bf, norm_w, ubf_of[p], mo_of[p]);
    }

    // 7. wbuf = silu(xn @ W_wp^T + b_wp)     (K=128,N=256) -> bf16
    k_gemm_bf<1><<<dim3(4, 64), 256, 0, stream>>>(xn_bf, wb_W_wp, b_wp, nullptr,
                                                  nullptr, wbuf_bf, NROW, 256, 128, 0);
    // 8+9. out = [wbuf*(mof+flip(mob))] @ W_out^T + b_out + x   (K=256,N=128), comb fused
    k_gemm_comb<<<dim3(2, 64), 256, 0, stream>>>(wbuf_bf, mof_bf, mob_bf, wb_W_out, b_out,
                                                 x, (float*)d_out, 128, 256);
}

// Round 10
// 266.249 us; speedup vs baseline: 7.7109x; 1.3389x over previous
//
#include <hip/hip_runtime.h>
#include <math.h>

#define C_LEN 1024
#define NROW 4096   // B*C = 4*1024
#define NCHUNK 32
#define CHUNK 32    // C_LEN / NCHUNK

typedef __attribute__((ext_vector_type(8))) short short8;
typedef __attribute__((ext_vector_type(4))) float f32x4;

__device__ __forceinline__ float siluf(float x) { return x / (1.f + __expf(-x)); }

__device__ __forceinline__ unsigned short f2bf(float f) {
    unsigned u = __builtin_bit_cast(unsigned, f);
    unsigned r = (u + 0x7FFFu + ((u >> 16) & 1u)) >> 16;
    return (unsigned short)r;
}
__device__ __forceinline__ float bf2f(unsigned short v) {
    unsigned u = ((unsigned)v) << 16;
    return __builtin_bit_cast(float, u);
}

// ---------------- weight fp32 -> bf16 conversion (once per launch) ----------------
struct WTab {
    const float* s[11];
    unsigned short* d[11];
    int n[11];
};
__global__ __launch_bounds__(256) void k_w2bf(WTab t) {
    int seg = blockIdx.y;
    int n = t.n[seg];
    int i = (blockIdx.x * 256 + threadIdx.x) * 4;
    if (i < n) {
        float4 v = *(const float4*)(t.s[seg] + i);
        unsigned short* o = t.d[seg] + i;
        o[0] = f2bf(v.x); o[1] = f2bf(v.y); o[2] = f2bf(v.z); o[3] = f2bf(v.w);
    }
}

// ---------------- rmsnorm over rows of width 128 -> bf16 out ----------------
__global__ __launch_bounds__(256) void k_rmsnorm128(const float* __restrict__ x,
                                                    const float* __restrict__ w,
                                                    unsigned short* __restrict__ out) {
    int wave = threadIdx.x >> 6, lane = threadIdx.x & 63;
    int row = blockIdx.x * 4 + wave;
    float2 v = ((const float2*)(x + (size_t)row * 128))[lane];
    float ss = v.x * v.x + v.y * v.y;
    #pragma unroll
    for (int off = 32; off; off >>= 1) ss += __shfl_xor(ss, off, 64);
    float rs = rsqrtf(ss * (1.f / 128.f) + 1e-5f);
    float2 wv = ((const float2*)w)[lane];
    ushort2 o;
    o.x = f2bf(v.x * rs * wv.x);
    o.y = f2bf(v.y * rs * wv.y);
    ((ushort2*)(out + (size_t)row * 128))[lane] = o;
}

// ---------------- single bf16 GEMM (step 2 only): bf16 out + bias ----------------
__global__ __launch_bounds__(256) void k_gemm_bf(const unsigned short* __restrict__ A,
                                                 const unsigned short* __restrict__ W,
                                                 const float* __restrict__ bias,
                                                 unsigned short* __restrict__ Cbf,
                                                 int N, int K) {
    __shared__ __align__(16) unsigned short As[64 * 72];
    __shared__ __align__(16) unsigned short Bs[64 * 72];
    int tid = threadIdx.x;
    int m0 = blockIdx.y * 64, n0 = blockIdx.x * 64;
    int w = tid >> 6, lane = tid & 63;
    int q = lane >> 4, ln = lane & 15;
    int srow = tid >> 2;
    int sseg = (tid & 3) * 16;

    const unsigned short* pa = A + (size_t)(m0 + srow) * K + sseg;
    const unsigned short* pw = W + (size_t)(n0 + srow) * K + sseg;

    f32x4 acc[4];
    #pragma unroll
    for (int j = 0; j < 4; ++j) acc[j] = (f32x4)(0.f);

    for (int k0 = 0; k0 < K; k0 += 64) {
        *(short8*)&As[srow * 72 + sseg]     = *(const short8*)pa;
        *(short8*)&As[srow * 72 + sseg + 8] = *(const short8*)(pa + 8);
        *(short8*)&Bs[srow * 72 + sseg]     = *(const short8*)pw;
        *(short8*)&Bs[srow * 72 + sseg + 8] = *(const short8*)(pw + 8);
        pa += 64; pw += 64;
        __syncthreads();
        short8 af0 = *(const short8*)&As[(w * 16 + ln) * 72 + q * 8];
        short8 af1 = *(const short8*)&As[(w * 16 + ln) * 72 + 32 + q * 8];
        #pragma unroll
        for (int j = 0; j < 4; ++j) {
            short8 bf0 = *(const short8*)&Bs[(j * 16 + ln) * 72 + q * 8];
            short8 bf1 = *(const short8*)&Bs[(j * 16 + ln) * 72 + 32 + q * 8];
            acc[j] = __builtin_amdgcn_mfma_f32_16x16x32_bf16(af0, bf0, acc[j], 0, 0, 0);
            acc[j] = __builtin_amdgcn_mfma_f32_16x16x32_bf16(af1, bf1, acc[j], 0, 0, 0);
        }
        __syncthreads();
    }
    #pragma unroll
    for (int j = 0; j < 4; ++j) {
        int nn = n0 + j * 16 + ln;
        float bsv = bias[nn];
        #pragma unroll
        for (int r = 0; r < 4; ++r) {
            int m = m0 + w * 16 + q * 4 + r;
            Cbf[(size_t)m * N + nn] = f2bf(acc[j][r] + bsv);
        }
    }
}

// ---------------- 3-way GEMM: z=0 uf (W_fp), z=1 ub (W_bp, flip), z=2 wbuf (W_wp, silu) ----
__global__ __launch_bounds__(256) void k_gemm3(
        const unsigned short* __restrict__ xn, const unsigned short* __restrict__ ssm,
        const unsigned short* __restrict__ Wfp, const unsigned short* __restrict__ Wbp,
        const unsigned short* __restrict__ Wwp,
        const float* __restrict__ bfp, const float* __restrict__ bbp,
        const float* __restrict__ bwp,
        unsigned short* __restrict__ uf, unsigned short* __restrict__ ub,
        unsigned short* __restrict__ wbuf) {
    __shared__ __align__(16) unsigned short As[64 * 72];
    __shared__ __align__(16) unsigned short Bs[64 * 72];
    int z = blockIdx.z;
    const unsigned short* A = (z == 2) ? xn : ssm;
    const unsigned short* W = (z == 0) ? Wfp : (z == 1) ? Wbp : Wwp;
    const float* bias = (z == 0) ? bfp : (z == 1) ? bbp : bwp;
    unsigned short* C = (z == 0) ? uf : (z == 1) ? ub : wbuf;
    int K = (z == 2) ? 128 : 256;
    int tid = threadIdx.x;
    int m0 = blockIdx.y * 64, n0 = blockIdx.x * 64;
    int w = tid >> 6, lane = tid & 63;
    int q = lane >> 4, ln = lane & 15;
    int srow = tid >> 2;
    int sseg = (tid & 3) * 16;

    int mLog = m0 + srow;
    int mPhys = (z == 1) ? (mLog ^ (C_LEN - 1)) : mLog;
    const unsigned short* pa = A + (size_t)mPhys * K + sseg;
    const unsigned short* pw = W + (size_t)(n0 + srow) * K + sseg;

    f32x4 acc[4];
    #pragma unroll
    for (int j = 0; j < 4; ++j) acc[j] = (f32x4)(0.f);

    for (int k0 = 0; k0 < K; k0 += 64) {
        *(short8*)&As[srow * 72 + sseg]     = *(const short8*)pa;
        *(short8*)&As[srow * 72 + sseg + 8] = *(const short8*)(pa + 8);
        *(short8*)&Bs[srow * 72 + sseg]     = *(const short8*)pw;
        *(short8*)&Bs[srow * 72 + sseg + 8] = *(const short8*)(pw + 8);
        pa += 64; pw += 64;
        __syncthreads();
        short8 af0 = *(const short8*)&As[(w * 16 + ln) * 72 + q * 8];
        short8 af1 = *(const short8*)&As[(w * 16 + ln) * 72 + 32 + q * 8];
        #pragma unroll
        for (int j = 0; j < 4; ++j) {
            short8 bf0 = *(const short8*)&Bs[(j * 16 + ln) * 72 + q * 8];
            short8 bf1 = *(const short8*)&Bs[(j * 16 + ln) * 72 + 32 + q * 8];
            acc[j] = __builtin_amdgcn_mfma_f32_16x16x32_bf16(af0, bf0, acc[j], 0, 0, 0);
            acc[j] = __builtin_amdgcn_mfma_f32_16x16x32_bf16(af1, bf1, acc[j], 0, 0, 0);
        }
        __syncthreads();
    }
    #pragma unroll
    for (int j = 0; j < 4; ++j) {
        int nn = n0 + j * 16 + ln;
        float bsv = bias[nn];
        #pragma unroll
        for (int r = 0; r < 4; ++r) {
            int m = m0 + w * 16 + q * 4 + r;
            float v = acc[j][r] + bsv;
            if (z == 2) v = siluf(v);
            C[(size_t)m * 256 + nn] = f2bf(v);
        }
    }
}

// ---------------- batched-pair GEMM (both mamba blocks): no bias/flip ----------------
__global__ __launch_bounds__(256) void k_gemm2(
        const unsigned short* __restrict__ A0, const unsigned short* __restrict__ A1,
        const unsigned short* __restrict__ W0, const unsigned short* __restrict__ W1,
        float* __restrict__ Cf0, float* __restrict__ Cf1,
        unsigned short* __restrict__ Cb0, unsigned short* __restrict__ Cb1,
        int N, int K) {
    __shared__ __align__(16) unsigned short As[64 * 72];
    __shared__ __align__(16) unsigned short Bs[64 * 72];
    int p = blockIdx.z;
    const unsigned short* A = p ? A1 : A0;
    const unsigned short* W = p ? W1 : W0;
    float* Cf = p ? Cf1 : Cf0;
    unsigned short* Cbf = p ? Cb1 : Cb0;
    int tid = threadIdx.x;
    int m0 = blockIdx.y * 64, n0 = blockIdx.x * 64;
    int w = tid >> 6, lane = tid & 63;
    int q = lane >> 4, ln = lane & 15;
    int srow = tid >> 2;
    int sseg = (tid & 3) * 16;

    const unsigned short* pa = A + (size_t)(m0 + srow) * K + sseg;
    int nIdx = n0 + srow;
    const unsigned short* pw = W + (size_t)nIdx * K + sseg;
    bool nOK = (nIdx < N);

    f32x4 acc[4];
    #pragma unroll
    for (int j = 0; j < 4; ++j) acc[j] = (f32x4)(0.f);

    for (int k0 = 0; k0 < K; k0 += 64) {
        *(short8*)&As[srow * 72 + sseg]     = *(const short8*)pa;
        *(short8*)&As[srow * 72 + sseg + 8] = *(const short8*)(pa + 8);
        short8 b0 = (short8)(0), b1 = (short8)(0);
        if (nOK) { b0 = *(const short8*)pw; b1 = *(const short8*)(pw + 8); }
        *(short8*)&Bs[srow * 72 + sseg] = b0;
        *(short8*)&Bs[srow * 72 + sseg + 8] = b1;
        pa += 64; pw += 64;
        __syncthreads();
        short8 af0 = *(const short8*)&As[(w * 16 + ln) * 72 + q * 8];
        short8 af1 = *(const short8*)&As[(w * 16 + ln) * 72 + 32 + q * 8];
        #pragma unroll
        for (int j = 0; j < 4; ++j) {
            short8 bf0 = *(const short8*)&Bs[(j * 16 + ln) * 72 + q * 8];
            short8 bf1 = *(const short8*)&Bs[(j * 16 + ln) * 72 + 32 + q * 8];
            acc[j] = __builtin_amdgcn_mfma_f32_16x16x32_bf16(af0, bf0, acc[j], 0, 0, 0);
            acc[j] = __builtin_amdgcn_mfma_f32_16x16x32_bf16(af1, bf1, acc[j], 0, 0, 0);
        }
        __syncthreads();
    }
    #pragma unroll
    for (int j = 0; j < 4; ++j) {
        int nn = n0 + j * 16 + ln;
        if (nn < N) {
            #pragma unroll
            for (int r = 0; r < 4; ++r) {
                int m = m0 + w * 16 + q * 4 + r;
                float v = acc[j][r];
                if (Cf)  Cf[(size_t)m * N + nn] = v;
                if (Cbf) Cbf[(size_t)m * N + nn] = f2bf(v);
            }
        }
    }
}

// ---------------- final GEMM with comb fused into A-staging ----------------
__global__ __launch_bounds__(256) void k_gemm_comb(const unsigned short* __restrict__ wbuf,
                                                   const unsigned short* __restrict__ mof,
                                                   const unsigned short* __restrict__ mob,
                                                   const unsigned short* __restrict__ W,
                                                   const float* __restrict__ bias,
                                                   const float* __restrict__ resid,
                                                   float* __restrict__ Cf,
                                                   int N, int K) {
    __shared__ __align__(16) unsigned short As[64 * 72];
    __shared__ __align__(16) unsigned short Bs[64 * 72];
    int tid = threadIdx.x;
    int m0 = blockIdx.y * 64, n0 = blockIdx.x * 64;
    int w = tid >> 6, lane = tid & 63;
    int q = lane >> 4, ln = lane & 15;
    int srow = tid >> 2;
    int sseg = (tid & 3) * 16;

    int mLog = m0 + srow;
    int mFlip = mLog ^ (C_LEN - 1);
    int nIdx = n0 + srow;
    const unsigned short* pw = W + (size_t)nIdx * K + sseg;
    bool nOK = (nIdx < N);

    f32x4 acc[4];
    #pragma unroll
    for (int j = 0; j < 4; ++j) acc[j] = (f32x4)(0.f);

    for (int k0 = 0; k0 < K; k0 += 64) {
        size_t off  = (size_t)mLog * 256 + k0 + sseg;
        size_t offb = (size_t)mFlip * 256 + k0 + sseg;
        #pragma unroll
        for (int h = 0; h < 2; ++h) {
            short8 aw = *(const short8*)(wbuf + off + h * 8);
            short8 af = *(const short8*)(mof + off + h * 8);
            short8 ab = *(const short8*)(mob + offb + h * 8);
            short8 av;
            #pragma unroll
            for (int j = 0; j < 8; ++j)
                av[j] = (short)f2bf(bf2f((unsigned short)aw[j]) *
                                    (bf2f((unsigned short)af[j]) + bf2f((unsigned short)ab[j])));
            *(short8*)&As[srow * 72 + sseg + h * 8] = av;
        }
        short8 b0 = (short8)(0), b1 = (short8)(0);
        if (nOK) { b0 = *(const short8*)pw; b1 = *(const short8*)(pw + 8); }
        *(short8*)&Bs[srow * 72 + sseg] = b0;
        *(short8*)&Bs[srow * 72 + sseg + 8] = b1;
        pw += 64;
        __syncthreads();
        short8 af0 = *(const short8*)&As[(w * 16 + ln) * 72 + q * 8];
        short8 af1 = *(const short8*)&As[(w * 16 + ln) * 72 + 32 + q * 8];
        #pragma unroll
        for (int j = 0; j < 4; ++j) {
            short8 bf0 = *(const short8*)&Bs[(j * 16 + ln) * 72 + q * 8];
            short8 bf1 = *(const short8*)&Bs[(j * 16 + ln) * 72 + 32 + q * 8];
            acc[j] = __builtin_amdgcn_mfma_f32_16x16x32_bf16(af0, bf0, acc[j], 0, 0, 0);
            acc[j] = __builtin_amdgcn_mfma_f32_16x16x32_bf16(af1, bf1, acc[j], 0, 0, 0);
        }
        __syncthreads();
    }
    #pragma unroll
    for (int j = 0; j < 4; ++j) {
        int nn = n0 + j * 16 + ln;
        if (nn < N) {
            float bsv = bias[nn];
            #pragma unroll
            for (int r = 0; r < 4; ++r) {
                int m = m0 + w * 16 + q * 4 + r;
                Cf[(size_t)m * N + nn] = acc[j][r] + bsv + resid[(size_t)m * N + nn];
            }
        }
    }
}

// ---------------- causal depthwise conv (K=4) + silu, both blocks ----------------
__global__ __launch_bounds__(256) void k_conv(const unsigned short* __restrict__ xz0,
                                              const unsigned short* __restrict__ xz1,
                                              const float* __restrict__ cw0,
                                              const float* __restrict__ cw1,
                                              const float* __restrict__ cb0,
                                              const float* __restrict__ cb1,
                                              unsigned short* __restrict__ xc0,
                                              unsigned short* __restrict__ xc1) {
    int pz = blockIdx.z;
    const unsigned short* xz = pz ? xz1 : xz0;
    const float* cw = pz ? cw1 : cw0;
    const float* cb = pz ? cb1 : cb0;
    unsigned short* xconv_bf = pz ? xc1 : xc0;
    int d = blockIdx.x * 256 + threadIdx.x;
    int by = blockIdx.y;
    int b = by >> 6, c0 = (by & 63) * 16;
    float4 cwv = *(const float4*)(cw + d * 4);
    float bias = cb[d];
    const unsigned short* base = xz + (size_t)(b * C_LEN) * 1024 + d;
    float w0 = 0.f, w1 = 0.f, w2 = 0.f;
    if (c0) {
        w0 = bf2f(base[(size_t)(c0 - 3) * 1024]);
        w1 = bf2f(base[(size_t)(c0 - 2) * 1024]);
        w2 = bf2f(base[(size_t)(c0 - 1) * 1024]);
    }
    unsigned short* out = xconv_bf + (size_t)(b * C_LEN + c0) * 512 + d;
    #pragma unroll
    for (int i = 0; i < 16; ++i) {
        float cur = bf2f(base[(size_t)(c0 + i) * 1024]);
        float acc = bias;
        acc = fmaf(cwv.x, w0, acc);
        acc = fmaf(cwv.y, w1, acc);
        acc = fmaf(cwv.z, w2, acc);
        acc = fmaf(cwv.w, cur, acc);
        out[(size_t)i * 512] = f2bf(siluf(acc));
        w0 = w1; w1 = w2; w2 = cur;
    }
}

// ---------------- dt projection, 8 rows per thread, both blocks ----------------
__global__ __launch_bounds__(256) void k_dtproj(const float* __restrict__ dbl0,
                                                const float* __restrict__ dbl1,
                                                const float* __restrict__ dtw0,
                                                const float* __restrict__ dtw1,
                                                const float* __restrict__ dtb0,
                                                const float* __restrict__ dtb1,
                                                float* __restrict__ dt0,
                                                float* __restrict__ dt1) {
    int pz = blockIdx.z;
    const float* dbl = pz ? dbl1 : dbl0;
    const float* dtw = pz ? dtw1 : dtw0;
    const float* dtb = pz ? dtb1 : dtb0;
    float* dt = pz ? dt1 : dt0;
    int d = blockIdx.x * 256 + threadIdx.x;
    int r0 = blockIdx.y * 8;
    float4 w0 = *(const float4*)(dtw + d * 16);
    float4 w1 = *(const float4*)(dtw + d * 16 + 4);
    float4 w2 = *(const float4*)(dtw + d * 16 + 8);
    float4 w3 = *(const float4*)(dtw + d * 16 + 12);
    float bias = dtb[d];
    #pragma unroll
    for (int rr = 0; rr < 8; ++rr) {
        int r = r0 + rr;
        const float* row = dbl + (size_t)r * 48;
        float s = bias;
        s = fmaf(row[0], w0.x, s);  s = fmaf(row[1], w0.y, s);
        s = fmaf(row[2], w0.z, s);  s = fmaf(row[3], w0.w, s);
        s = fmaf(row[4], w1.x, s);  s = fmaf(row[5], w1.y, s);
        s = fmaf(row[6], w1.z, s);  s = fmaf(row[7], w1.w, s);
        s = fmaf(row[8], w2.x, s);  s = fmaf(row[9], w2.y, s);
        s = fmaf(row[10], w2.z, s); s = fmaf(row[11], w2.w, s);
        s = fmaf(row[12], w3.x, s); s = fmaf(row[13], w3.y, s);
        s = fmaf(row[14], w3.z, s); s = fmaf(row[15], w3.w, s);
        float sp = fmaxf(s, 0.f) + log1pf(__expf(-fabsf(s)));
        dt[(size_t)r * 512 + d] = sp;
    }
}

// ---------------- chunked selective scan, pass 1, both blocks ----------------
__global__ __launch_bounds__(256) void k_scan1(const float* __restrict__ dt0,
                                               const float* __restrict__ dt1,
                                               const unsigned short* __restrict__ xc0,
                                               const unsigned short* __restrict__ xc1,
                                               const float* __restrict__ dblA,
                                               const float* __restrict__ dblB,
                                               const float* __restrict__ alog0,
                                               const float* __restrict__ alog1,
                                               float* __restrict__ hfin0,
                                               float* __restrict__ hfin1,
                                               float* __restrict__ Pfin0,
                                               float* __restrict__ Pfin1) {
    int z = blockIdx.z;
    int b = z & 3, p = z >> 2;
    const float* dt = p ? dt1 : dt0;
    const unsigned short* xconv_bf = p ? xc1 : xc0;
    const float* dbl = p ? dblB : dblA;
    const float* A_log = p ? alog1 : alog0;
    float* hfin = p ? hfin1 : hfin0;
    float* Pfin = p ? Pfin1 : Pfin0;
    int tid = threadIdx.x;
    int nh = tid & 1, dl = tid >> 1;
    int k = blockIdx.x, dg = blockIdx.y;
    int d = dg * 128 + dl;
    float4 al0 = *(const float4*)&A_log[d * 16 + nh * 8];
    float4 al1 = *(const float4*)&A_log[d * 16 + nh * 8 + 4];
    float Ac[8] = {-__expf(al0.x), -__expf(al0.y), -__expf(al0.z), -__expf(al0.w),
                   -__expf(al1.x), -__expf(al1.y), -__expf(al1.z), -__expf(al1.w)};
    size_t r0 = (size_t)(b * C_LEN + k * CHUNK);
    const float* pdt = dt + r0 * 512 + d;
    const unsigned short* pxv = xconv_bf + r0 * 512 + d;
    const float* pB  = dbl + r0 * 48 + 16 + nh * 8;
    float h[8] = {0.f, 0.f, 0.f, 0.f, 0.f, 0.f, 0.f, 0.f};
    float sdt = 0.f;
    #pragma unroll 8
    for (int c = 0; c < CHUNK; ++c) {
        float dtv = *pdt;
        float xv  = bf2f(*pxv);
        float4 B0 = *(const float4*)pB;
        float4 B1 = *(const float4*)(pB + 4);
        float dx = dtv * xv;
        float Bv[8] = {B0.x, B0.y, B0.z, B0.w, B1.x, B1.y, B1.z, B1.w};
        #pragma unroll
        for (int j = 0; j < 8; ++j)
            h[j] = fmaf(__expf(dtv * Ac[j]), h[j], dx * Bv[j]);
        sdt += dtv;
        pdt += 512; pxv += 512; pB += 48;
    }
    size_t idx = ((size_t)(b * NCHUNK + k) * 512 + d) * 16 + nh * 8;
    *(float4*)&hfin[idx]     = make_float4(h[0], h[1], h[2], h[3]);
    *(float4*)&hfin[idx + 4] = make_float4(h[4], h[5], h[6], h[7]);
    *(float4*)&Pfin[idx]     = make_float4(__expf(Ac[0] * sdt), __expf(Ac[1] * sdt),
                                           __expf(Ac[2] * sdt), __expf(Ac[3] * sdt));
    *(float4*)&Pfin[idx + 4] = make_float4(__expf(Ac[4] * sdt), __expf(Ac[5] * sdt),
                                           __expf(Ac[6] * sdt), __expf(Ac[7] * sdt));
}

// ---------------- pass 2: sequential combine over chunks, both blocks ----------------
__global__ __launch_bounds__(256) void k_scan2(const float* __restrict__ hfin0,
                                               const float* __restrict__ hfin1,
                                               float* __restrict__ Pfin0,
                                               float* __restrict__ Pfin1) {
    int tt = blockIdx.x * 256 + threadIdx.x;   // 0..65535
    int p = tt >> 15;
    int t = tt & 32767;
    const float* hfin = p ? hfin1 : hfin0;
    float* Pfin = p ? Pfin1 : Pfin0;
    int b = t >> 13;
    int dn = t & 8191;
    float carry = 0.f;
    #pragma unroll
    for (int k = 0; k < NCHUNK; ++k) {
        size_t idx = (size_t)(b * NCHUNK + k) * 8192 + dn;
        float pv = Pfin[idx];
        float hf = hfin[idx];
        Pfin[idx] = carry;
        carry = fmaf(pv, carry, hf);
    }
}

// ---------------- pass 3: replay with carry-in; y + D skip + z gate, both blocks ---------
__global__ __launch_bounds__(256) void k_scan3(const float* __restrict__ dt0,
                                               const float* __restrict__ dt1,
                                               const unsigned short* __restrict__ xc0,
                                               const unsigned short* __restrict__ xc1,
                                               const float* __restrict__ dblA,
                                               const float* __restrict__ dblB,
                                               const unsigned short* __restrict__ xz0,
                                               const unsigned short* __restrict__ xz1,
                                               const float* __restrict__ alog0,
                                               const float* __restrict__ alog1,
                                               const float* __restrict__ Dp0,
                                               const float* __restrict__ Dp1,
                                               const float* __restrict__ carry0,
                                               const float* __restrict__ carry1,
                                               unsigned short* __restrict__ g0,
                                               unsigned short* __restrict__ g1) {
    int z = blockIdx.z;
    int b = z & 3, p = z >> 2;
    const float* dt = p ? dt1 : dt0;
    const unsigned short* xconv_bf = p ? xc1 : xc0;
    const float* dbl = p ? dblB : dblA;
    const unsigned short* xz = p ? xz1 : xz0;
    const float* A_log = p ? alog1 : alog0;
    const float* Dp = p ? Dp1 : Dp0;
    const float* carryArr = p ? carry1 : carry0;
    unsigned short* gated_bf = p ? g1 : g0;
    int tid = threadIdx.x;
    int nh = tid & 1, dl = tid >> 1;
    int k = blockIdx.x, dg = blockIdx.y;
    int d = dg * 128 + dl;
    float4 al0 = *(const float4*)&A_log[d * 16 + nh * 8];
    float4 al1 = *(const float4*)&A_log[d * 16 + nh * 8 + 4];
    float Ac[8] = {-__expf(al0.x), -__expf(al0.y), -__expf(al0.z), -__expf(al0.w),
                   -__expf(al1.x), -__expf(al1.y), -__expf(al1.z), -__expf(al1.w)};
    float Dd = Dp[d];
    size_t idx = ((size_t)(b * NCHUNK + k) * 512 + d) * 16 + nh * 8;
    float4 h0 = *(const float4*)&carryArr[idx];
    float4 h1 = *(const float4*)&carryArr[idx + 4];
    float h[8] = {h0.x, h0.y, h0.z, h0.w, h1.x, h1.y, h1.z, h1.w};
    size_t r0 = (size_t)(b * C_LEN + k * CHUNK);
    const float* pdt = dt + r0 * 512 + d;
    const unsigned short* pxv = xconv_bf + r0 * 512 + d;
    const float* pB  = dbl + r0 * 48 + 16 + nh * 8;
    const float* pC  = dbl + r0 * 48 + 32 + nh * 8;
    const unsigned short* pz = xz + r0 * 1024 + 512 + d;
    unsigned short* pg = gated_bf + r0 * 512 + d;
    #pragma unroll 4
    for (int c = 0; c < CHUNK; ++c) {
        float dtv = *pdt;
        float xv  = bf2f(*pxv);
        float4 B0 = *(const float4*)pB;
        float4 B1 = *(const float4*)(pB + 4);
        float4 C0 = *(const float4*)pC;
        float4 C1 = *(const float4*)(pC + 4);
        float dx = dtv * xv;
        float Bv[8] = {B0.x, B0.y, B0.z, B0.w, B1.x, B1.y, B1.z, B1.w};
        float Cv[8] = {C0.x, C0.y, C0.z, C0.w, C1.x, C1.y, C1.z, C1.w};
        float contrib = 0.f;
        #pragma unroll
        for (int j = 0; j < 8; ++j) {
            h[j] = fmaf(__expf(dtv * Ac[j]), h[j], dx * Bv[j]);
            contrib = fmaf(h[j], Cv[j], contrib);
        }
        contrib += __shfl_xor(contrib, 1, 64);
        if (nh == 0) {
            float y = contrib + xv * Dd;
            float zv = bf2f(*pz);
            *pg = f2bf(y * siluf(zv));
        }
        pdt += 512; pxv += 512; pB += 48; pC += 48; pz += 1024; pg += 512;
    }
}

// ---------------- postnorm both blocks: rmsnorm(mo)*w + u -> bf16 ----------------
__global__ __launch_bounds__(256) void k_postnorm(const unsigned short* __restrict__ mo0,
                                                  const unsigned short* __restrict__ mo1,
                                                  const float* __restrict__ w0,
                                                  const float* __restrict__ w1,
                                                  const unsigned short* __restrict__ u0,
                                                  const unsigned short* __restrict__ u1,
                                                  unsigned short* __restrict__ o0,
                                                  unsigned short* __restrict__ o1) {
    __shared__ float red[4];
    int p = blockIdx.y;
    const unsigned short* mo = p ? mo1 : mo0;
    const float* w = p ? w1 : w0;
    const unsigned short* u = p ? u1 : u0;
    unsigned short* out = p ? o1 : o0;
    int r = blockIdx.x, tid = threadIdx.x;
    float v = bf2f(mo[(size_t)r * 256 + tid]);
    float ss = v * v;
    #pragma unroll
    for (int off = 32; off; off >>= 1) ss += __shfl_xor(ss, off, 64);
    if ((tid & 63) == 0) red[tid >> 6] = ss;
    __syncthreads();
    float tot = red[0] + red[1] + red[2] + red[3];
    float rs = rsqrtf(tot * (1.f / 256.f) + 1e-5f);
    out[(size_t)r * 256 + tid] = f2bf(v * rs * w[tid] + bf2f(u[(size_t)r * 256 + tid]));
}

extern "C" void kernel_launch(void* const* d_in, const int* in_sizes, int n_in,
                              void* d_out, int out_size, void* d_ws, size_t ws_size,
                              hipStream_t stream) {
    const float* x          = (const float*)d_in[0];
    const float* W_in       = (const float*)d_in[1];
    const float* b_in       = (const float*)d_in[2];
    const float* W_wp       = (const float*)d_in[3];
    const float* b_wp       = (const float*)d_in[4];
    const float* W_fp       = (const float*)d_in[5];
    const float* b_fp       = (const float*)d_in[6];
    const float* W_bp       = (const float*)d_in[7];
    const float* b_bp       = (const float*)d_in[8];
    const float* W_out      = (const float*)d_in[9];
    const float* b_out      = (const float*)d_in[10];
    const float* norm_w_top = (const float*)d_in[11];
    const float* mamba_p[2][10];
    for (int p = 0; p < 2; ++p)
        for (int i = 0; i < 10; ++i)
            mamba_p[p][i] = (const float*)d_in[12 + p * 10 + i];

    // ---- workspace: fp32 region (8781824 floats) then bf16 region; total 88.6 MB ----
    float* ws = (float*)d_ws;
    float* dblP[2]  = {ws + 0,       ws + 196608};
    float* dtbP[2]  = {ws + 393216,  ws + 2490368};
    float* hfinP[2] = {ws + 4587520, ws + 5636096};
    float* PfinP[2] = {ws + 6684672, ws + 7733248};   // fp32 end: 8781824

    unsigned short* us = (unsigned short*)(ws + 8781824);
    unsigned short* xn_bf   = us + 0;          // 524288
    unsigned short* ssm_bf  = us + 524288;     // 1048576
    unsigned short* uf_bf   = us + 1572864;    // 1048576
    unsigned short* ub_bf   = us + 2621440;    // 1048576
    unsigned short* wbuf_bf = us + 3670016;    // 1048576
    unsigned short* xzP[2]  = {us + 4718592,  us + 8912896};   // 4194304 each
    unsigned short* xcP[2]  = {us + 13107200, us + 15204352};  // 2097152 each
    unsigned short* gP[2]   = {us + 17301504, us + 19398656};  // 2097152 each
    unsigned short* moP[2]  = {us + 21495808, us + 22544384};  // 1048576 each (moraw)
    unsigned short* mof_bf  = us + 23592960;   // 1048576
    unsigned short* mob_bf  = us + 24641536;   // 1048576
    unsigned short* wb      = us + 25690112;   // weights (1064960) -> end 26755072
    unsigned short* wb_W_in  = wb + 0;
    unsigned short* wb_W_wp  = wb + 32768;
    unsigned short* wb_W_fp  = wb + 65536;
    unsigned short* wb_W_bp  = wb + 131072;
    unsigned short* wb_W_out = wb + 196608;
    unsigned short* wb_in[2]  = {wb + 229376, wb + 647168};
    unsigned short* wb_xp[2]  = {wb + 491520, wb + 909312};
    unsigned short* wb_outw[2]= {wb + 516096, wb + 933888};

    // 0. convert all weights to bf16
    WTab t;
    t.s[0] = W_in;            t.d[0] = wb_W_in;   t.n[0] = 32768;
    t.s[1] = W_wp;            t.d[1] = wb_W_wp;   t.n[1] = 32768;
    t.s[2] = W_fp;            t.d[2] = wb_W_fp;   t.n[2] = 65536;
    t.s[3] = W_bp;            t.d[3] = wb_W_bp;   t.n[3] = 65536;
    t.s[4] = W_out;           t.d[4] = wb_W_out;  t.n[4] = 32768;
    t.s[5] = mamba_p[0][0];   t.d[5] = wb_in[0];  t.n[5] = 262144;
    t.s[6] = mamba_p[0][3];   t.d[6] = wb_xp[0];  t.n[6] = 24576;
    t.s[7] = mamba_p[0][8];   t.d[7] = wb_outw[0];t.n[7] = 131072;
    t.s[8] = mamba_p[1][0];   t.d[8] = wb_in[1];  t.n[8] = 262144;
    t.s[9] = mamba_p[1][3];   t.d[9] = wb_xp[1];  t.n[9] = 24576;
    t.s[10]= mamba_p[1][8];   t.d[10]= wb_outw[1];t.n[10]= 131072;
    k_w2bf<<<dim3(256, 11), 256, 0, stream>>>(t);

    // 1. top rmsnorm -> bf16
    k_rmsnorm128<<<NROW / 4, 256, 0, stream>>>(x, norm_w_top, xn_bf);
    // 2. ssm = xn @ W_in^T + b_in (K=128,N=256) -> bf16
    k_gemm_bf<<<dim3(4, 64), 256, 0, stream>>>(xn_bf, wb_W_in, b_in, ssm_bf, 256, 128);
    // 3. uf / ub / wbuf in one 3-way launch
    k_gemm3<<<dim3(4, 64, 3), 256, 0, stream>>>(xn_bf, ssm_bf, wb_W_fp, wb_W_bp, wb_W_wp,
                                                b_fp, b_bp, b_wp, uf_bf, ub_bf, wbuf_bf);

    // 4. both mamba blocks batched over blockIdx.z
    // xz = u @ in_w^T (K=256,N=1024) -> bf16
    k_gemm2<<<dim3(16, 64, 2), 256, 0, stream>>>(uf_bf, ub_bf, wb_in[0], wb_in[1],
                                                 nullptr, nullptr, xzP[0], xzP[1], 1024, 256);
    // conv + silu -> bf16
    k_conv<<<dim3(2, 256, 2), 256, 0, stream>>>(xzP[0], xzP[1],
                                                mamba_p[0][1], mamba_p[1][1],
                                                mamba_p[0][2], mamba_p[1][2],
                                                xcP[0], xcP[1]);
    // dbl = xconv @ xproj_w^T (K=512,N=48) -> fp32
    k_gemm2<<<dim3(1, 64, 2), 256, 0, stream>>>(xcP[0], xcP[1], wb_xp[0], wb_xp[1],
                                                dblP[0], dblP[1], nullptr, nullptr, 48, 512);
    // dt = softplus(dbl[:, :16] @ dt_w^T + dt_b)
    k_dtproj<<<dim3(2, 512, 2), 256, 0, stream>>>(dblP[0], dblP[1],
                                                  mamba_p[0][4], mamba_p[1][4],
                                                  mamba_p[0][5], mamba_p[1][5],
                                                  dtbP[0], dtbP[1]);
    // scans
    k_scan1<<<dim3(NCHUNK, 4, 8), 256, 0, stream>>>(dtbP[0], dtbP[1], xcP[0], xcP[1],
                                                    dblP[0], dblP[1],
                                                    mamba_p[0][6], mamba_p[1][6],
                                                    hfinP[0], hfinP[1], PfinP[0], PfinP[1]);
    k_scan2<<<256, 256, 0, stream>>>(hfinP[0], hfinP[1], PfinP[0], PfinP[1]);
    k_scan3<<<dim3(NCHUNK, 4, 8), 256, 0, stream>>>(dtbP[0], dtbP[1], xcP[0], xcP[1],
                                                    dblP[0], dblP[1], xzP[0], xzP[1],
                                                    mamba_p[0][6], mamba_p[1][6],
                                                    mamba_p[0][7], mamba_p[1][7],
                                                    PfinP[0], PfinP[1], gP[0], gP[1]);
    // mo_raw = gated @ out_w^T (K=512,N=256) -> bf16
    k_gemm2<<<dim3(4, 64, 2), 256, 0, stream>>>(gP[0], gP[1], wb_outw[0], wb_outw[1],
                                                nullptr, nullptr, moP[0], moP[1], 256, 512);
    // postnorm both
    k_postnorm<<<dim3(NROW, 2), 256, 0, stream>>>(moP[0], moP[1],
                                                  mamba_p[0][9], mamba_p[1][9],
                                                  uf_bf, ub_bf, mof_bf, mob_bf);

    // 5. out = [wbuf*(mof+flip(mob))] @ W_out^T + b_out + x (K=256,N=128)
    k_gemm_comb<<<dim3(2, 64), 256, 0, stream>>>(wbuf_bf, mof_bf, mob_bf, wb_W_out, b_out,
                                                 x, (float*)d_out, 128, 256);
}